// Round 2
// baseline (291.222 us; speedup 1.0000x reference)
//
#include <hip/hip_runtime.h>

#define TTILE 32
#define DEC 256
#define TFULL 4096
#define CIN 32
#define HROW 164   // 64 x 164 floats, padded (164%32==4 -> conflict-free)
#define SROW 33    // 64 x 33 floats, padded
#define WS_PER_LAYER 20480  // fw 8192 + gw 8192 + pw 4096 floats
#define WS_FLOATS (8 * WS_PER_LAYER)           // 163840 floats of weights
#define P_FLOATS (8ull * 256 * 2048)           // partials: [L][b*8+tile][o*32+t]

__device__ __forceinline__ float fast_tanh(float x) {
    float xa = fminf(fmaxf(x, -10.f), 10.f);
    float e = __expf(2.f * xa);
    return (e - 1.f) * __builtin_amdgcn_rcpf(e + 1.f);
}

// ---------------- prep: transpose weights into ws ----------------
// ws per layer i (floats): [0,8192)  fw[c][o][k]   (from filt_w[i][o][c][k])
//                          [8192,16384) gw[c][o][k]
//                          [16384,20480) pw[c][o]   (from post_w[i][o][c])
__global__ __launch_bounds__(512) void wavenet_prep(
    const float* __restrict__ fw, const float* __restrict__ gw,
    const float* __restrict__ pw, float* __restrict__ ws)
{
    int idx = blockIdx.x * 512 + threadIdx.x;
    const int total = WS_FLOATS;
    const int stride = gridDim.x * 512;
    for (; idx < total; idx += stride) {
        int layer = idx / WS_PER_LAYER;
        int r = idx - layer * WS_PER_LAYER;
        float v;
        if (r < 8192) {
            int c = r >> 7, rem = r & 127, o = rem >> 1, k = r & 1;
            v = fw[((layer * 64 + o) * 64 + c) * 2 + k];
        } else if (r < 16384) {
            int r2 = r - 8192;
            int c = r2 >> 7, rem = r2 & 127, o = rem >> 1, k = r2 & 1;
            v = gw[((layer * 64 + o) * 64 + c) * 2 + k];
        } else {
            int r3 = r - 16384;
            int c = r3 >> 6, o = r3 & 63;
            v = pw[(layer * 64 + o) * 64 + c];
        }
        ws[idx] = v;
    }
}

// ---------------- layer-parallel main kernel ----------------
// grid = 2048: bid -> layer i = bid&7, b = (bid>>3)>>3, tile = (bid>>3)&7
__global__ __launch_bounds__(512, 6) void wavenet_layer(
    const float* __restrict__ x,
    const float* __restrict__ pre_w, const float* __restrict__ pre_b,
    const float* __restrict__ filt_b, const float* __restrict__ gate_b,
    const float* __restrict__ post_b,
    const float* __restrict__ wsw, float* __restrict__ pout)
{
    __shared__ __align__(16) float h_s[64 * HROW]; // 41984 B
    __shared__ __align__(16) float s_s[64 * SROW]; //  8448 B

    const int tid = threadIdx.x;
    const int i = blockIdx.x & 7;
    const int bt = blockIdx.x >> 3;
    const int b = bt >> 3;
    const int tile = bt & 7;
    const int dil = 1 << i;
    const int t0 = TFULL - DEC + tile * TTILE;
    const int NC = TTILE + dil;

    const int lane = tid & 63;
    const int wv = __builtin_amdgcn_readfirstlane(tid >> 6); // uniform wave id
    const int q = tid >> 5;   // 0..15
    const int tt = tid & 31;  // t within tile

    // ---- phase 1: h[c][col] = relu(pre_w x + pre_b), col in [0,NC) ----
    {
        const float* preb = pre_b + i * 64 + wv * 8;
        const float* prew = pre_w + (i * 64 + wv * 8) * CIN; // wave-uniform base
        for (int col = lane; col < NC; col += 64) {
            int ta = t0 - dil + col;
            const float* xp = x + b * CIN * TFULL + ta;
            float hacc[8];
#pragma unroll
            for (int r = 0; r < 8; ++r) hacc[r] = preb[r];
            for (int ci = 0; ci < CIN; ++ci) {
                float xv = xp[ci * TFULL]; // coalesced over lanes
#pragma unroll
                for (int r = 0; r < 8; ++r)
                    hacc[r] = fmaf(prew[r * CIN + ci], xv, hacc[r]);
            }
#pragma unroll
            for (int r = 0; r < 8; ++r)
                h_s[(wv * 8 + r) * HROW + col] = fmaxf(hacc[r], 0.f);
        }
    }
    __syncthreads();

    // ---- phase 2: f,g,s  (o = 4q+oo, t = tt); weights from global (L2) ----
    {
        float fa[4], ga[4];
        const float* fb = filt_b + i * 64 + q * 4;
        const float* gb = gate_b + i * 64 + q * 4;
#pragma unroll
        for (int oo = 0; oo < 4; ++oo) { fa[oo] = fb[oo]; ga[oo] = gb[oo]; }
        const float4* fw4 = (const float4*)(wsw + i * WS_PER_LAYER) + q * 2;
        const float4* gw4 = (const float4*)(wsw + i * WS_PER_LAYER + 8192) + q * 2;
        const float* hrow0 = h_s + tt;
        const float* hrow1 = h_s + tt + dil;
#pragma unroll 2
        for (int c = 0; c < 64; ++c) {
            float4 f0 = fw4[c * 32];
            float4 f1 = fw4[c * 32 + 1];
            float4 g0 = gw4[c * 32];
            float4 g1 = gw4[c * 32 + 1];
            float h0 = hrow0[c * HROW]; // tap w[...,0] * x[t-dil]
            float h1 = hrow1[c * HROW]; // tap w[...,1] * x[t]
            fa[0] = fmaf(f0.x, h0, fmaf(f0.y, h1, fa[0]));
            fa[1] = fmaf(f0.z, h0, fmaf(f0.w, h1, fa[1]));
            fa[2] = fmaf(f1.x, h0, fmaf(f1.y, h1, fa[2]));
            fa[3] = fmaf(f1.z, h0, fmaf(f1.w, h1, fa[3]));
            ga[0] = fmaf(g0.x, h0, fmaf(g0.y, h1, ga[0]));
            ga[1] = fmaf(g0.z, h0, fmaf(g0.w, h1, ga[1]));
            ga[2] = fmaf(g1.x, h0, fmaf(g1.y, h1, ga[2]));
            ga[3] = fmaf(g1.z, h0, fmaf(g1.w, h1, ga[3]));
        }
#pragma unroll
        for (int oo = 0; oo < 4; ++oo)
            s_s[(q * 4 + oo) * SROW + tt] = fast_tanh(fa[oo]) * fmaxf(ga[oo], 0.f);
    }
    __syncthreads();

    // ---- phase 3: post conv -> relu'd skip partial to global ----
    {
        float pa[4];
        const float* pb = post_b + i * 64 + q * 4;
#pragma unroll
        for (int oo = 0; oo < 4; ++oo) pa[oo] = pb[oo];
        const float4* pw4 = (const float4*)(wsw + i * WS_PER_LAYER + 16384) + q;
#pragma unroll 2
        for (int c = 0; c < 64; ++c) {
            float4 pv = pw4[c * 16];
            float sv = s_s[c * SROW + tt];
            pa[0] = fmaf(pv.x, sv, pa[0]);
            pa[1] = fmaf(pv.y, sv, pa[1]);
            pa[2] = fmaf(pv.z, sv, pa[2]);
            pa[3] = fmaf(pv.w, sv, pa[3]);
        }
        float* po = pout + ((size_t)(i * 256 + b * 8 + tile)) * 2048 + tt;
#pragma unroll
        for (int oo = 0; oo < 4; ++oo)
            po[(q * 4 + oo) * 32] = fmaxf(pa[oo], 0.f);
    }
}

// ---------------- head: skip-sum + dense 64 -> 128 -> 1 ----------------
__global__ __launch_bounds__(512) void wavenet_head(
    const float* __restrict__ pin,
    const float* __restrict__ d1_w, const float* __restrict__ d1_b,
    const float* __restrict__ d2_w, const float* __restrict__ d2_b,
    float* __restrict__ out)
{
    __shared__ __align__(16) float s_s[64 * SROW];
    __shared__ float red[512];
    const int tid = threadIdx.x;
    const int b = blockIdx.x >> 3;
    const int tile = blockIdx.x & 7;
    const int q = tid >> 5, tt = tid & 31;

    float a[4] = {0.f, 0.f, 0.f, 0.f};
    for (int l = 0; l < 8; ++l) {
        const float* p = pin + ((size_t)(l * 256 + b * 8 + tile)) * 2048 + tt;
#pragma unroll
        for (int oo = 0; oo < 4; ++oo) a[oo] += p[(q * 4 + oo) * 32];
    }
#pragma unroll
    for (int oo = 0; oo < 4; ++oo) s_s[(q * 4 + oo) * SROW + tt] = a[oo];
    __syncthreads();

    {
        const int pg = tid >> 5; // 16 groups x 8 p
        float partial = 0.f;
#pragma unroll
        for (int pp = 0; pp < 8; ++pp) {
            const int p = pg * 8 + pp;
            float z = d1_b[p];
            const float4* w4 = (const float4*)(d1_w + p * 64);
#pragma unroll 4
            for (int c4 = 0; c4 < 16; ++c4) {
                float4 w = w4[c4];
                z = fmaf(w.x, s_s[(c4 * 4 + 0) * SROW + tt], z);
                z = fmaf(w.y, s_s[(c4 * 4 + 1) * SROW + tt], z);
                z = fmaf(w.z, s_s[(c4 * 4 + 2) * SROW + tt], z);
                z = fmaf(w.w, s_s[(c4 * 4 + 3) * SROW + tt], z);
            }
            partial = fmaf(d2_w[p], fmaxf(z, 0.f), partial);
        }
        red[pg * 32 + tt] = partial;
    }
    __syncthreads();
    if (tid < 32) {
        float sum = d2_b[0];
#pragma unroll
        for (int g = 0; g < 16; ++g) sum += red[g * 32 + tid];
        out[b * DEC + tile * TTILE + tid] = fmaxf(sum, 0.f);
    }
}

// ================= fallback: round-1 fused kernel =================
__global__ __launch_bounds__(512) void wavenet_main(
    const float* __restrict__ x,
    const float* __restrict__ pre_w, const float* __restrict__ pre_b,
    const float* __restrict__ filt_w, const float* __restrict__ filt_b,
    const float* __restrict__ gate_w, const float* __restrict__ gate_b,
    const float* __restrict__ post_w, const float* __restrict__ post_b,
    const float* __restrict__ d1_w, const float* __restrict__ d1_b,
    const float* __restrict__ d2_w, const float* __restrict__ d2_b,
    const float* __restrict__ ws, int use_ws,
    float* __restrict__ out)
{
    __shared__ __align__(16) float h_s[64 * HROW];
    __shared__ __align__(16) float wbuf[WS_PER_LAYER];
    __shared__ __align__(16) float s_s[64 * SROW];

    const int tid = threadIdx.x;
    const int b = blockIdx.x >> 3;
    const int tile = blockIdx.x & 7;
    const int t0 = TFULL - DEC + tile * TTILE;

    const int lane = tid & 63;
    const int wv = __builtin_amdgcn_readfirstlane(tid >> 6);
    const int q = tid >> 5;
    const int tt = tid & 31;

    float accp[4] = {0.f, 0.f, 0.f, 0.f};

    for (int i = 0; i < 8; ++i) {
        const int dil = 1 << i;
        const int NC = TTILE + dil;

        if (use_ws) {
            const float4* src = (const float4*)(ws + i * WS_PER_LAYER);
            float4* dst = (float4*)wbuf;
            for (int j = tid; j < WS_PER_LAYER / 4; j += 512) dst[j] = src[j];
        } else {
            for (int m = tid; m < 8192; m += 512) {
                int c = m >> 7, rem = m & 127, o = rem >> 1, k = m & 1;
                wbuf[m] = filt_w[((i * 64 + o) * 64 + c) * 2 + k];
                wbuf[8192 + m] = gate_w[((i * 64 + o) * 64 + c) * 2 + k];
            }
            for (int m = tid; m < 4096; m += 512) {
                int c = m >> 6, o = m & 63;
                wbuf[16384 + m] = post_w[(i * 64 + o) * 64 + c];
            }
        }
        __syncthreads();

        {
            const float* preb = pre_b + i * 64 + wv * 8;
            const float* prew = pre_w + (i * 64 + wv * 8) * CIN;
            for (int col = lane; col < NC; col += 64) {
                int ta = t0 - dil + col;
                const float* xp = x + b * CIN * TFULL + ta;
                float hacc[8];
#pragma unroll
                for (int r = 0; r < 8; ++r) hacc[r] = preb[r];
                for (int ci = 0; ci < CIN; ++ci) {
                    float xv = xp[ci * TFULL];
#pragma unroll
                    for (int r = 0; r < 8; ++r)
                        hacc[r] = fmaf(prew[r * CIN + ci], xv, hacc[r]);
                }
#pragma unroll
                for (int r = 0; r < 8; ++r)
                    h_s[(wv * 8 + r) * HROW + col] = fmaxf(hacc[r], 0.f);
            }
        }
        __syncthreads();

        {
            float fa[4], ga[4];
#pragma unroll
            for (int oo = 0; oo < 4; ++oo) {
                fa[oo] = filt_b[i * 64 + q * 4 + oo];
                ga[oo] = gate_b[i * 64 + q * 4 + oo];
            }
            const float4* fw4 = (const float4*)wbuf;
            const float4* gw4 = (const float4*)(wbuf + 8192);
            const float* hrow0 = h_s + tt;
            const float* hrow1 = h_s + tt + dil;
#pragma unroll 4
            for (int c = 0; c < 64; ++c) {
                float4 f0 = fw4[c * 32 + q * 2];
                float4 f1 = fw4[c * 32 + q * 2 + 1];
                float4 g0 = gw4[c * 32 + q * 2];
                float4 g1 = gw4[c * 32 + q * 2 + 1];
                float h0 = hrow0[c * HROW];
                float h1 = hrow1[c * HROW];
                fa[0] = fmaf(f0.x, h0, fmaf(f0.y, h1, fa[0]));
                fa[1] = fmaf(f0.z, h0, fmaf(f0.w, h1, fa[1]));
                fa[2] = fmaf(f1.x, h0, fmaf(f1.y, h1, fa[2]));
                fa[3] = fmaf(f1.z, h0, fmaf(f1.w, h1, fa[3]));
                ga[0] = fmaf(g0.x, h0, fmaf(g0.y, h1, ga[0]));
                ga[1] = fmaf(g0.z, h0, fmaf(g0.w, h1, ga[1]));
                ga[2] = fmaf(g1.x, h0, fmaf(g1.y, h1, ga[2]));
                ga[3] = fmaf(g1.z, h0, fmaf(g1.w, h1, ga[3]));
            }
#pragma unroll
            for (int oo = 0; oo < 4; ++oo) {
                float sv = fast_tanh(fa[oo]) * fmaxf(ga[oo], 0.f);
                s_s[(q * 4 + oo) * SROW + tt] = sv;
            }
        }
        __syncthreads();

        {
            float pa[4];
#pragma unroll
            for (int oo = 0; oo < 4; ++oo) pa[oo] = post_b[i * 64 + q * 4 + oo];
            const float4* pw4 = (const float4*)(wbuf + 16384);
#pragma unroll 4
            for (int c = 0; c < 64; ++c) {
                float4 pv = pw4[c * 16 + q];
                float sv = s_s[c * SROW + tt];
                pa[0] = fmaf(pv.x, sv, pa[0]);
                pa[1] = fmaf(pv.y, sv, pa[1]);
                pa[2] = fmaf(pv.z, sv, pa[2]);
                pa[3] = fmaf(pv.w, sv, pa[3]);
            }
#pragma unroll
            for (int oo = 0; oo < 4; ++oo) accp[oo] += fmaxf(pa[oo], 0.f);
        }
        __syncthreads();
    }

#pragma unroll
    for (int oo = 0; oo < 4; ++oo) s_s[(q * 4 + oo) * SROW + tt] = accp[oo];
    __syncthreads();

    {
        const int pg = tid >> 5;
        float partial = 0.f;
#pragma unroll
        for (int pp = 0; pp < 8; ++pp) {
            const int p = pg * 8 + pp;
            float z = d1_b[p];
            const float4* w4 = (const float4*)(d1_w + p * 64);
#pragma unroll 4
            for (int c4 = 0; c4 < 16; ++c4) {
                float4 w = w4[c4];
                z = fmaf(w.x, s_s[(c4 * 4 + 0) * SROW + tt], z);
                z = fmaf(w.y, s_s[(c4 * 4 + 1) * SROW + tt], z);
                z = fmaf(w.z, s_s[(c4 * 4 + 2) * SROW + tt], z);
                z = fmaf(w.w, s_s[(c4 * 4 + 3) * SROW + tt], z);
            }
            partial = fmaf(d2_w[p], fmaxf(z, 0.f), partial);
        }
        h_s[pg * 32 + tt] = partial;
    }
    __syncthreads();
    if (tid < 32) {
        float sum = d2_b[0];
#pragma unroll
        for (int g = 0; g < 16; ++g) sum += h_s[g * 32 + tid];
        out[b * DEC + tile * TTILE + tid] = fmaxf(sum, 0.f);
    }
}

extern "C" void kernel_launch(void* const* d_in, const int* in_sizes, int n_in,
                              void* d_out, int out_size, void* d_ws, size_t ws_size,
                              hipStream_t stream)
{
    const float* x      = (const float*)d_in[0];
    const float* pre_w  = (const float*)d_in[1];
    const float* pre_b  = (const float*)d_in[2];
    const float* filt_w = (const float*)d_in[3];
    const float* filt_b = (const float*)d_in[4];
    const float* gate_w = (const float*)d_in[5];
    const float* gate_b = (const float*)d_in[6];
    const float* post_w = (const float*)d_in[7];
    const float* post_b = (const float*)d_in[8];
    const float* d1_w   = (const float*)d_in[9];
    const float* d1_b   = (const float*)d_in[10];
    const float* d2_w   = (const float*)d_in[11];
    const float* d2_b   = (const float*)d_in[12];
    float* out = (float*)d_out;
    float* ws  = (float*)d_ws;

    const size_t need_full = ((size_t)WS_FLOATS + P_FLOATS) * sizeof(float);
    if (ws_size >= need_full) {
        wavenet_prep<<<160, 512, 0, stream>>>(filt_w, gate_w, post_w, ws);
        wavenet_layer<<<2048, 512, 0, stream>>>(
            x, pre_w, pre_b, filt_b, gate_b, post_b, ws, ws + WS_FLOATS);
        wavenet_head<<<256, 512, 0, stream>>>(
            ws + WS_FLOATS, d1_w, d1_b, d2_w, d2_b, out);
    } else {
        const int use_ws = (ws_size >= (size_t)WS_FLOATS * sizeof(float)) ? 1 : 0;
        if (use_ws) {
            wavenet_prep<<<160, 512, 0, stream>>>(filt_w, gate_w, post_w, ws);
        }
        wavenet_main<<<256, 512, 0, stream>>>(
            x, pre_w, pre_b, filt_w, filt_b, gate_w, gate_b, post_w, post_b,
            d1_w, d1_b, d2_w, d2_b, ws, use_ws, out);
    }
}

// Round 3
// 97.099 us; speedup vs baseline: 2.9992x; 2.9992x over previous
//
#include <hip/hip_runtime.h>

typedef _Float16 half2_t __attribute__((ext_vector_type(2)));

#define DEC 256
#define TFULL 4096
#define WIN0 3584               // x window start (t0min-128 = 3712 >= 3584)
#define WLAYER_U32 11264        // pre16 1024 + f 4096 + g 4096 + p 2048
#define WTOT_U32 (8 * WLAYER_U32)          // 90112
#define X16_U32 (32 * 16 * 512)            // 262144
#define WS_NEED ((size_t)(WTOT_U32 + X16_U32) * 4)

__device__ __forceinline__ float fast_tanh(float x) {
    float xa = fminf(fmaxf(x, -10.f), 10.f);
    float e = __expf(2.f * xa);
    return (e - 1.f) * __builtin_amdgcn_rcpf(e + 1.f);
}
__device__ __forceinline__ unsigned pk_rte(float a, float b) {
    union { _Float16 h[2]; unsigned u; } v;
    v.h[0] = (_Float16)a; v.h[1] = (_Float16)b; return v.u;
}
__device__ __forceinline__ half2_t h2(unsigned u) {
    return __builtin_bit_cast(half2_t, u);
}
__device__ __forceinline__ unsigned pkrtz(float a, float b) {
    return __builtin_bit_cast(unsigned, __builtin_amdgcn_cvt_pkrtz(a, b));
}
__device__ __forceinline__ float fdot2(unsigned w, unsigned hp, float acc) {
    return __builtin_amdgcn_fdot2(h2(w), h2(hp), acc, false);
}

// ---------------- prep: pack weights + x window to f16x2 ----------------
// per-layer block (u32): [0,1024) pre16[o64][cp16]
//                        [1024,5120)  f16 [ci16][q16][cs4][oo4]  c=cs*16+ci, o=4q+oo
//                        [5120,9216)  g16 same
//                        [9216,11264) p16 [cpi8][q16][cs4][oo4]  cp=cs*8+cpi
// then x16[b32][cp16][tw512] at WTOT_U32.
__global__ __launch_bounds__(512) void wavenet_prep16(
    const float* __restrict__ x,
    const float* __restrict__ pre_w,
    const float* __restrict__ fw, const float* __restrict__ gw,
    const float* __restrict__ pw, unsigned* __restrict__ ws)
{
    int idx = blockIdx.x * 512 + threadIdx.x;
    if (idx >= WTOT_U32 + X16_U32) return;
    unsigned v;
    if (idx < WTOT_U32) {
        int i = idx / WLAYER_U32;
        int r = idx - i * WLAYER_U32;
        if (r < 1024) {
            int o = r >> 4, cp = r & 15;
            const float* p = pre_w + (i * 64 + o) * 32 + 2 * cp;
            v = pk_rte(p[0], p[1]);
        } else if (r < 5120) {
            int e = r - 1024;
            int ci = e >> 8, q = (e >> 4) & 15, cs = (e >> 2) & 3, oo = e & 3;
            int c = cs * 16 + ci, o = 4 * q + oo;
            const float* p = fw + ((i * 64 + o) * 64 + c) * 2;
            v = pk_rte(p[0], p[1]);
        } else if (r < 9216) {
            int e = r - 5120;
            int ci = e >> 8, q = (e >> 4) & 15, cs = (e >> 2) & 3, oo = e & 3;
            int c = cs * 16 + ci, o = 4 * q + oo;
            const float* p = gw + ((i * 64 + o) * 64 + c) * 2;
            v = pk_rte(p[0], p[1]);
        } else {
            int e = r - 9216;
            int cpi = e >> 8, q = (e >> 4) & 15, cs = (e >> 2) & 3, oo = e & 3;
            int cp = cs * 8 + cpi, o = 4 * q + oo;
            const float* p = pw + (i * 64 + o) * 64 + 2 * cp;
            v = pk_rte(p[0], p[1]);
        }
    } else {
        int e = idx - WTOT_U32;
        int b = e >> 13, r2 = e & 8191;
        int cp = r2 >> 9, tw = r2 & 511;
        const float* p = x + (size_t)(b * 32 + 2 * cp) * TFULL + WIN0 + tw;
        v = pk_rte(p[0], p[TFULL]);
    }
    ws[idx] = v;
}

// ---------------- fused f16-dot2 main kernel ----------------
// grid 256 = (b32, tile8), 512 threads. LDS 57344 B -> 2 blocks/CU.
// lane bits: cs = tid&3, tg = (tid>>2)&7, q = tid>>5  (cs in low bits =>
// cs-reduction is shfl_xor 1/2 = quad-perm DPP, off the LDS pipe).
__global__ __launch_bounds__(512, 4) void wavenet_f16(
    const unsigned* __restrict__ wsu,
    const float* __restrict__ pre_b,
    const float* __restrict__ filt_b, const float* __restrict__ gate_b,
    const float* __restrict__ post_b,
    const float* __restrict__ d1_w, const float* __restrict__ d1_b,
    const float* __restrict__ d2_w, const float* __restrict__ d2_b,
    float* __restrict__ out)
{
    __shared__ __align__(16) unsigned lds[14336];  // 57344 B
    // [0,11264) staged layer weights; [11264,13312) hp16[c64][t32];
    // [13312,14336) s16[cp32][t32]

    const int tid = threadIdx.x;
    const int b = blockIdx.x >> 3;
    const int tile = blockIdx.x & 7;
    const int t0 = TFULL - DEC + tile * 32;

    const int lane = tid & 63;
    const int wv = __builtin_amdgcn_readfirstlane(tid >> 6);
    const int cs = tid & 3;
    const int tg = (tid >> 2) & 7;
    const int q = tid >> 5;

    const unsigned* xw = wsu + WTOT_U32 + b * 8192;

    float accp[16];
#pragma unroll
    for (int k = 0; k < 16; ++k) accp[k] = 0.f;

    for (int i = 0; i < 8; ++i) {
        const int dil = 1 << i;
        const int off1 = (dil < 32) ? dil : 32;

        // ---- stage this layer's packed weights (44 KB) ----
        {
            const float4* src = (const float4*)(wsu + i * WLAYER_U32);
            float4* dst = (float4*)lds;
            for (int j = tid; j < WLAYER_U32 / 4; j += 512) dst[j] = src[j];
        }
        __syncthreads();

        // ---- phase 1: h = relu(pre16 . x16), pair taps -> hp16 ----
        {
            const int col = lane;
            int ta = (dil >= 32) ? ((col < 32) ? (t0 - dil + col) : (t0 + col - 32))
                                 : (t0 - dil + col);
            const int tw = (ta - WIN0) & 511;   // clamp OOB idle lanes in-window
            const unsigned* xp = xw + tw;
            // pre weights read from global (wave-uniform address -> scalar-friendly)
            const unsigned* pw_g = wsu + i * WLAYER_U32 + wv * 128;
            float h[8];
#pragma unroll
            for (int r = 0; r < 8; ++r) h[r] = pre_b[i * 64 + wv * 8 + r];
#pragma unroll
            for (int cpb = 0; cpb < 4; ++cpb) {
                unsigned xv0 = xp[(cpb * 4 + 0) * 512];
                unsigned xv1 = xp[(cpb * 4 + 1) * 512];
                unsigned xv2 = xp[(cpb * 4 + 2) * 512];
                unsigned xv3 = xp[(cpb * 4 + 3) * 512];
#pragma unroll
                for (int r = 0; r < 8; ++r) {
                    uint4 wq = *(const uint4*)(pw_g + r * 16 + cpb * 4);
                    h[r] = fdot2(wq.x, xv0, h[r]);
                    h[r] = fdot2(wq.y, xv1, h[r]);
                    h[r] = fdot2(wq.z, xv2, h[r]);
                    h[r] = fdot2(wq.w, xv3, h[r]);
                }
            }
            const int pl = (col - off1) & 63;
            const bool wr = (col >= off1) && (col < off1 + 32);
            const int tt = col - off1;
#pragma unroll
            for (int r = 0; r < 8; ++r) {
                float hv = fmaxf(h[r], 0.f);
                float hp0 = __shfl(hv, pl, 64);   // partner = tap0 = h[t-dil]
                if (wr) lds[11264 + (wv * 8 + r) * 32 + tt] = pkrtz(hp0, hv);
            }
        }
        __syncthreads();

        // ---- phase 2: f,g (4o x 4t x 16c per thread) + tanh*relu -> s16 ----
        {
            float fa[16], ga[16];
#pragma unroll
            for (int k = 0; k < 16; ++k) { fa[k] = 0.f; ga[k] = 0.f; }
            const unsigned* fb_ = lds + 1024 + q * 16 + cs * 4;
            const unsigned* gb_ = lds + 5120 + q * 16 + cs * 4;
            const unsigned* hp_ = lds + 11264 + cs * 512 + tg * 4;
#pragma unroll 2
            for (int ci = 0; ci < 16; ++ci) {
                uint4 fw4 = *(const uint4*)(fb_ + ci * 256);
                uint4 gw4 = *(const uint4*)(gb_ + ci * 256);
                uint4 hp4 = *(const uint4*)(hp_ + ci * 32);
                unsigned fwa[4] = {fw4.x, fw4.y, fw4.z, fw4.w};
                unsigned gwa[4] = {gw4.x, gw4.y, gw4.z, gw4.w};
                unsigned hpa[4] = {hp4.x, hp4.y, hp4.z, hp4.w};
#pragma unroll
                for (int oo = 0; oo < 4; ++oo)
#pragma unroll
                    for (int j = 0; j < 4; ++j) {
                        fa[oo * 4 + j] = fdot2(fwa[oo], hpa[j], fa[oo * 4 + j]);
                        ga[oo * 4 + j] = fdot2(gwa[oo], hpa[j], ga[oo * 4 + j]);
                    }
            }
            // reduce over cs (lane bits 0-1 -> quad-perm DPP)
#pragma unroll
            for (int k = 0; k < 16; ++k) {
                fa[k] += __shfl_xor(fa[k], 1, 64);
                fa[k] += __shfl_xor(fa[k], 2, 64);
                ga[k] += __shfl_xor(ga[k], 1, 64);
                ga[k] += __shfl_xor(ga[k], 2, 64);
            }
            if (cs < 2) {
                const int r0 = 4 * q + 2 * cs;
                float fb0 = filt_b[i * 64 + r0], fb1 = filt_b[i * 64 + r0 + 1];
                float gb0 = gate_b[i * 64 + r0], gb1 = gate_b[i * 64 + r0 + 1];
                uint4 sv4;
                float s0, s1;
                s0 = fast_tanh(fa[(2 * cs) * 4 + 0] + fb0) * fmaxf(ga[(2 * cs) * 4 + 0] + gb0, 0.f);
                s1 = fast_tanh(fa[(2 * cs + 1) * 4 + 0] + fb1) * fmaxf(ga[(2 * cs + 1) * 4 + 0] + gb1, 0.f);
                sv4.x = pkrtz(s0, s1);
                s0 = fast_tanh(fa[(2 * cs) * 4 + 1] + fb0) * fmaxf(ga[(2 * cs) * 4 + 1] + gb0, 0.f);
                s1 = fast_tanh(fa[(2 * cs + 1) * 4 + 1] + fb1) * fmaxf(ga[(2 * cs + 1) * 4 + 1] + gb1, 0.f);
                sv4.y = pkrtz(s0, s1);
                s0 = fast_tanh(fa[(2 * cs) * 4 + 2] + fb0) * fmaxf(ga[(2 * cs) * 4 + 2] + gb0, 0.f);
                s1 = fast_tanh(fa[(2 * cs + 1) * 4 + 2] + fb1) * fmaxf(ga[(2 * cs + 1) * 4 + 2] + gb1, 0.f);
                sv4.z = pkrtz(s0, s1);
                s0 = fast_tanh(fa[(2 * cs) * 4 + 3] + fb0) * fmaxf(ga[(2 * cs) * 4 + 3] + gb0, 0.f);
                s1 = fast_tanh(fa[(2 * cs + 1) * 4 + 3] + fb1) * fmaxf(ga[(2 * cs + 1) * 4 + 3] + gb1, 0.f);
                sv4.w = pkrtz(s0, s1);
                *(uint4*)(lds + 13312 + (2 * q + cs) * 32 + tg * 4) = sv4;
            }
        }
        __syncthreads();

        // ---- phase 3: post conv (4o x 4t x 8cp per thread) -> skip acc ----
        {
            float pa[16];
#pragma unroll
            for (int k = 0; k < 16; ++k) pa[k] = 0.f;
            const unsigned* pb_ = lds + 9216 + q * 16 + cs * 4;
            const unsigned* sp_ = lds + 13312 + cs * 256 + tg * 4;
#pragma unroll 2
            for (int cpi = 0; cpi < 8; ++cpi) {
                uint4 pw4 = *(const uint4*)(pb_ + cpi * 256);
                uint4 sv4 = *(const uint4*)(sp_ + cpi * 32);
                unsigned pwa[4] = {pw4.x, pw4.y, pw4.z, pw4.w};
                unsigned sva[4] = {sv4.x, sv4.y, sv4.z, sv4.w};
#pragma unroll
                for (int oo = 0; oo < 4; ++oo)
#pragma unroll
                    for (int j = 0; j < 4; ++j)
                        pa[oo * 4 + j] = fdot2(pwa[oo], sva[j], pa[oo * 4 + j]);
            }
#pragma unroll
            for (int k = 0; k < 16; ++k) {
                pa[k] += __shfl_xor(pa[k], 1, 64);
                pa[k] += __shfl_xor(pa[k], 2, 64);
            }
#pragma unroll
            for (int oo = 0; oo < 4; ++oo) {
                float pb = post_b[i * 64 + 4 * q + oo];
#pragma unroll
                for (int j = 0; j < 4; ++j)
                    accp[oo * 4 + j] += fmaxf(pa[oo * 4 + j] + pb, 0.f);
            }
        }
        __syncthreads();
    }

    // ---- acc -> LDS (f32, stride 33) ----
    float* accf = (float*)lds;
    if (cs == 0) {
#pragma unroll
        for (int oo = 0; oo < 4; ++oo)
#pragma unroll
            for (int j = 0; j < 4; ++j)
                accf[(4 * q + oo) * 33 + (4 * tg + j)] = accp[oo * 4 + j];
    }
    __syncthreads();

    // ---- head: dense 64 -> 128 -> 1 ----
    {
        float* red = (float*)(lds + 11264);
        const int pg = tid >> 5, tt = tid & 31;
        float partial = 0.f;
#pragma unroll
        for (int pp = 0; pp < 8; ++pp) {
            const int p = pg * 8 + pp;
            float z = d1_b[p];
            const float4* w4 = (const float4*)(d1_w + p * 64);
#pragma unroll 4
            for (int c4 = 0; c4 < 16; ++c4) {
                float4 w = w4[c4];
                z = fmaf(w.x, accf[(c4 * 4 + 0) * 33 + tt], z);
                z = fmaf(w.y, accf[(c4 * 4 + 1) * 33 + tt], z);
                z = fmaf(w.z, accf[(c4 * 4 + 2) * 33 + tt], z);
                z = fmaf(w.w, accf[(c4 * 4 + 3) * 33 + tt], z);
            }
            partial = fmaf(d2_w[p], fmaxf(z, 0.f), partial);
        }
        red[pg * 32 + tt] = partial;
    }
    __syncthreads();
    if (tid < 32) {
        float* red = (float*)(lds + 11264);
        float sum = d2_b[0];
#pragma unroll
        for (int g = 0; g < 16; ++g) sum += red[g * 32 + tid];
        out[b * DEC + tile * 32 + tid] = fmaxf(sum, 0.f);
    }
}

// ================= fallback: round-1 fused fp32 kernel (no ws) =================
#define HROW 164
#define SROW 33
__global__ __launch_bounds__(512) void wavenet_main(
    const float* __restrict__ x,
    const float* __restrict__ pre_w, const float* __restrict__ pre_b,
    const float* __restrict__ filt_w, const float* __restrict__ filt_b,
    const float* __restrict__ gate_w, const float* __restrict__ gate_b,
    const float* __restrict__ post_w, const float* __restrict__ post_b,
    const float* __restrict__ d1_w, const float* __restrict__ d1_b,
    const float* __restrict__ d2_w, const float* __restrict__ d2_b,
    float* __restrict__ out)
{
    __shared__ __align__(16) float h_s[64 * HROW];
    __shared__ __align__(16) float wbuf[20480];
    __shared__ __align__(16) float s_s[64 * SROW];

    const int tid = threadIdx.x;
    const int b = blockIdx.x >> 3;
    const int tile = blockIdx.x & 7;
    const int t0 = TFULL - DEC + tile * 32;
    const int lane = tid & 63;
    const int wv = __builtin_amdgcn_readfirstlane(tid >> 6);
    const int q = tid >> 5;
    const int tt = tid & 31;
    float accp[4] = {0.f, 0.f, 0.f, 0.f};

    for (int i = 0; i < 8; ++i) {
        const int dil = 1 << i;
        const int NC = 32 + dil;
        for (int m = tid; m < 8192; m += 512) {
            int c = m >> 7, rem = m & 127, o = rem >> 1, k = m & 1;
            wbuf[m] = filt_w[((i * 64 + o) * 64 + c) * 2 + k];
            wbuf[8192 + m] = gate_w[((i * 64 + o) * 64 + c) * 2 + k];
        }
        for (int m = tid; m < 4096; m += 512) {
            int c = m >> 6, o = m & 63;
            wbuf[16384 + m] = post_w[(i * 64 + o) * 64 + c];
        }
        __syncthreads();
        {
            const float* preb = pre_b + i * 64 + wv * 8;
            const float* prew = pre_w + (i * 64 + wv * 8) * 32;
            for (int col = lane; col < NC; col += 64) {
                int ta = t0 - dil + col;
                const float* xp = x + (size_t)b * 32 * TFULL + ta;
                float hacc[8];
#pragma unroll
                for (int r = 0; r < 8; ++r) hacc[r] = preb[r];
                for (int ci = 0; ci < 32; ++ci) {
                    float xv = xp[ci * TFULL];
#pragma unroll
                    for (int r = 0; r < 8; ++r)
                        hacc[r] = fmaf(prew[r * 32 + ci], xv, hacc[r]);
                }
#pragma unroll
                for (int r = 0; r < 8; ++r)
                    h_s[(wv * 8 + r) * HROW + col] = fmaxf(hacc[r], 0.f);
            }
        }
        __syncthreads();
        {
            float fa[4], ga[4];
#pragma unroll
            for (int oo = 0; oo < 4; ++oo) {
                fa[oo] = filt_b[i * 64 + q * 4 + oo];
                ga[oo] = gate_b[i * 64 + q * 4 + oo];
            }
            const float4* fw4 = (const float4*)wbuf;
            const float4* gw4 = (const float4*)(wbuf + 8192);
            const float* hrow0 = h_s + tt;
            const float* hrow1 = h_s + tt + dil;
#pragma unroll 4
            for (int c = 0; c < 64; ++c) {
                float4 f0 = fw4[c * 32 + q * 2];
                float4 f1 = fw4[c * 32 + q * 2 + 1];
                float4 g0 = gw4[c * 32 + q * 2];
                float4 g1 = gw4[c * 32 + q * 2 + 1];
                float h0 = hrow0[c * HROW];
                float h1 = hrow1[c * HROW];
                fa[0] = fmaf(f0.x, h0, fmaf(f0.y, h1, fa[0]));
                fa[1] = fmaf(f0.z, h0, fmaf(f0.w, h1, fa[1]));
                fa[2] = fmaf(f1.x, h0, fmaf(f1.y, h1, fa[2]));
                fa[3] = fmaf(f1.z, h0, fmaf(f1.w, h1, fa[3]));
                ga[0] = fmaf(g0.x, h0, fmaf(g0.y, h1, ga[0]));
                ga[1] = fmaf(g0.z, h0, fmaf(g0.w, h1, ga[1]));
                ga[2] = fmaf(g1.x, h0, fmaf(g1.y, h1, ga[2]));
                ga[3] = fmaf(g1.z, h0, fmaf(g1.w, h1, ga[3]));
            }
#pragma unroll
            for (int oo = 0; oo < 4; ++oo)
                s_s[(q * 4 + oo) * SROW + tt] = fast_tanh(fa[oo]) * fmaxf(ga[oo], 0.f);
        }
        __syncthreads();
        {
            float pa[4];
#pragma unroll
            for (int oo = 0; oo < 4; ++oo) pa[oo] = post_b[i * 64 + q * 4 + oo];
            const float4* pw4 = (const float4*)(wbuf + 16384);
#pragma unroll 4
            for (int c = 0; c < 64; ++c) {
                float4 pv = pw4[c * 16 + q];
                float sv = s_s[c * SROW + tt];
                pa[0] = fmaf(pv.x, sv, pa[0]);
                pa[1] = fmaf(pv.y, sv, pa[1]);
                pa[2] = fmaf(pv.z, sv, pa[2]);
                pa[3] = fmaf(pv.w, sv, pa[3]);
            }
#pragma unroll
            for (int oo = 0; oo < 4; ++oo) accp[oo] += fmaxf(pa[oo], 0.f);
        }
        __syncthreads();
    }
#pragma unroll
    for (int oo = 0; oo < 4; ++oo) s_s[(q * 4 + oo) * SROW + tt] = accp[oo];
    __syncthreads();
    {
        const int pg = tid >> 5;
        float partial = 0.f;
#pragma unroll
        for (int pp = 0; pp < 8; ++pp) {
            const int p = pg * 8 + pp;
            float z = d1_b[p];
            const float4* w4 = (const float4*)(d1_w + p * 64);
#pragma unroll 4
            for (int c4 = 0; c4 < 16; ++c4) {
                float4 w = w4[c4];
                z = fmaf(w.x, s_s[(c4 * 4 + 0) * SROW + tt], z);
                z = fmaf(w.y, s_s[(c4 * 4 + 1) * SROW + tt], z);
                z = fmaf(w.z, s_s[(c4 * 4 + 2) * SROW + tt], z);
                z = fmaf(w.w, s_s[(c4 * 4 + 3) * SROW + tt], z);
            }
            partial = fmaf(d2_w[p], fmaxf(z, 0.f), partial);
        }
        h_s[pg * 32 + tt] = partial;
    }
    __syncthreads();
    if (tid < 32) {
        float sum = d2_b[0];
#pragma unroll
        for (int g = 0; g < 16; ++g) sum += h_s[g * 32 + tid];
        out[b * DEC + tile * 32 + tid] = fmaxf(sum, 0.f);
    }
}

extern "C" void kernel_launch(void* const* d_in, const int* in_sizes, int n_in,
                              void* d_out, int out_size, void* d_ws, size_t ws_size,
                              hipStream_t stream)
{
    const float* x      = (const float*)d_in[0];
    const float* pre_w  = (const float*)d_in[1];
    const float* pre_b  = (const float*)d_in[2];
    const float* filt_w = (const float*)d_in[3];
    const float* filt_b = (const float*)d_in[4];
    const float* gate_w = (const float*)d_in[5];
    const float* gate_b = (const float*)d_in[6];
    const float* post_w = (const float*)d_in[7];
    const float* post_b = (const float*)d_in[8];
    const float* d1_w   = (const float*)d_in[9];
    const float* d1_b   = (const float*)d_in[10];
    const float* d2_w   = (const float*)d_in[11];
    const float* d2_b   = (const float*)d_in[12];
    float* out = (float*)d_out;

    if (ws_size >= WS_NEED) {
        unsigned* ws = (unsigned*)d_ws;
        wavenet_prep16<<<688, 512, 0, stream>>>(x, pre_w, filt_w, gate_w, post_w, ws);
        wavenet_f16<<<256, 512, 0, stream>>>(
            ws, pre_b, filt_b, gate_b, post_b, d1_w, d1_b, d2_w, d2_b, out);
    } else {
        wavenet_main<<<256, 512, 0, stream>>>(
            x, pre_w, pre_b, filt_w, filt_b, gate_w, gate_b, post_w, post_b,
            d1_w, d1_b, d2_w, d2_b, out);
    }
}

// Round 4
// 81.257 us; speedup vs baseline: 3.5840x; 1.1950x over previous
//
#include <hip/hip_runtime.h>

typedef _Float16 half2_t __attribute__((ext_vector_type(2)));

#define DEC 256
#define TFULL 4096
#define WIN0 3584               // x window start (t0min-128 = 3712 >= 3584)
#define WLAYER_U32 11264        // pre16 1024 + f 4096 + g 4096 + p 2048
#define WTOT_U32 (8 * WLAYER_U32)          // 90112
#define X16_U32 (32 * 16 * 512)            // 262144
#define P_U32 (8 * 256 * 1024)             // skip partials, f16x2 packed
#define WS_NEED ((size_t)(WTOT_U32 + X16_U32) * 4)
#define WS_NEED2 ((size_t)(WTOT_U32 + X16_U32 + P_U32) * 4)

__device__ __forceinline__ float fast_tanh(float x) {
    float xa = fminf(fmaxf(x, -10.f), 10.f);
    float e = __expf(2.f * xa);
    return (e - 1.f) * __builtin_amdgcn_rcpf(e + 1.f);
}
__device__ __forceinline__ unsigned pk_rte(float a, float b) {
    union { _Float16 h[2]; unsigned u; } v;
    v.h[0] = (_Float16)a; v.h[1] = (_Float16)b; return v.u;
}
__device__ __forceinline__ half2_t h2(unsigned u) {
    return __builtin_bit_cast(half2_t, u);
}
__device__ __forceinline__ unsigned pkrtz(float a, float b) {
    return __builtin_bit_cast(unsigned, __builtin_amdgcn_cvt_pkrtz(a, b));
}
__device__ __forceinline__ float fdot2(unsigned w, unsigned hp, float acc) {
    return __builtin_amdgcn_fdot2(h2(w), h2(hp), acc, false);
}

// ---------------- prep: pack weights + x window to f16x2 ----------------
__global__ __launch_bounds__(512) void wavenet_prep16(
    const float* __restrict__ x,
    const float* __restrict__ pre_w,
    const float* __restrict__ fw, const float* __restrict__ gw,
    const float* __restrict__ pw, unsigned* __restrict__ ws)
{
    int idx = blockIdx.x * 512 + threadIdx.x;
    if (idx >= WTOT_U32 + X16_U32) return;
    unsigned v;
    if (idx < WTOT_U32) {
        int i = idx / WLAYER_U32;
        int r = idx - i * WLAYER_U32;
        if (r < 1024) {
            int o = r >> 4, cp = r & 15;
            const float* p = pre_w + (i * 64 + o) * 32 + 2 * cp;
            v = pk_rte(p[0], p[1]);
        } else if (r < 5120) {
            int e = r - 1024;
            int ci = e >> 8, q = (e >> 4) & 15, cs = (e >> 2) & 3, oo = e & 3;
            int c = cs * 16 + ci, o = 4 * q + oo;
            const float* p = fw + ((i * 64 + o) * 64 + c) * 2;
            v = pk_rte(p[0], p[1]);
        } else if (r < 9216) {
            int e = r - 5120;
            int ci = e >> 8, q = (e >> 4) & 15, cs = (e >> 2) & 3, oo = e & 3;
            int c = cs * 16 + ci, o = 4 * q + oo;
            const float* p = gw + ((i * 64 + o) * 64 + c) * 2;
            v = pk_rte(p[0], p[1]);
        } else {
            int e = r - 9216;
            int cpi = e >> 8, q = (e >> 4) & 15, cs = (e >> 2) & 3, oo = e & 3;
            int cp = cs * 8 + cpi, o = 4 * q + oo;
            const float* p = pw + (i * 64 + o) * 64 + 2 * cp;
            v = pk_rte(p[0], p[1]);
        }
    } else {
        int e = idx - WTOT_U32;
        int b = e >> 13, r2 = e & 8191;
        int cp = r2 >> 9, tw = r2 & 511;
        const float* p = x + (size_t)(b * 32 + 2 * cp) * TFULL + WIN0 + tw;
        v = pk_rte(p[0], p[TFULL]);
    }
    ws[idx] = v;
}

// ---------------- layer-parallel f16 kernel ----------------
// grid 2048 = layer(8) x b(32) x tile(8); 512 threads; LDS 53248 B -> 3 blk/CU.
__global__ __launch_bounds__(512) void wavenet_layer16(
    const unsigned* __restrict__ wsu,
    const float* __restrict__ pre_b,
    const float* __restrict__ filt_b, const float* __restrict__ gate_b,
    const float* __restrict__ post_b,
    unsigned* __restrict__ pout)
{
    __shared__ __align__(16) unsigned lds[13312];
    // [0,4096) f16, [4096,8192) g16, [8192,10240) p16,
    // [10240,12288) hp16[c64][t32] swz(col ^ ((c>>4)&3)<<3),
    // [12288,13312) s16[32][32]  swz(col ^ (((r>>3)^r)&3)<<3)

    const int tid = threadIdx.x;
    const int i = blockIdx.x >> 8;
    const int bt = blockIdx.x & 255;
    const int b = bt >> 3;
    const int tile = bt & 7;
    const int dil = 1 << i;
    const int off1 = (dil < 32) ? dil : 32;
    const int t0 = TFULL - DEC + tile * 32;

    const int lane = tid & 63;
    const int wv = __builtin_amdgcn_readfirstlane(tid >> 6);
    const int cs = tid & 3;
    const int tg = (tid >> 2) & 7;
    const int q = tid >> 5;

    // ---- stage f/g/p weights (40 KB) -- overlapped with phase 1 ----
    {
        const float4* src = (const float4*)(wsu + i * WLAYER_U32 + 1024);
        float4* dst = (float4*)lds;
#pragma unroll
        for (int j = 0; j < 5; ++j) dst[tid + j * 512] = src[tid + j * 512];
    }

    // ---- phase 1: h = relu(pre16 . x16), pair taps -> hp16 (swizzled) ----
    {
        const int col = lane;
        int ta = (dil >= 32) ? ((col < 32) ? (t0 - dil + col) : (t0 + col - 32))
                             : (t0 - dil + col);
        const int tw = (ta - WIN0) & 511;   // wrap OOB idle lanes in-window
        const unsigned* xp = wsu + WTOT_U32 + b * 8192 + tw;
        const unsigned* pw_g = wsu + i * WLAYER_U32 + wv * 128; // wave-uniform
        float h[8];
#pragma unroll
        for (int r = 0; r < 8; ++r) h[r] = pre_b[i * 64 + wv * 8 + r];
#pragma unroll
        for (int cpb = 0; cpb < 4; ++cpb) {
            unsigned xv0 = xp[(cpb * 4 + 0) * 512];
            unsigned xv1 = xp[(cpb * 4 + 1) * 512];
            unsigned xv2 = xp[(cpb * 4 + 2) * 512];
            unsigned xv3 = xp[(cpb * 4 + 3) * 512];
#pragma unroll
            for (int r = 0; r < 8; ++r) {
                uint4 wq = *(const uint4*)(pw_g + r * 16 + cpb * 4);
                h[r] = fdot2(wq.x, xv0, h[r]);
                h[r] = fdot2(wq.y, xv1, h[r]);
                h[r] = fdot2(wq.z, xv2, h[r]);
                h[r] = fdot2(wq.w, xv3, h[r]);
            }
        }
        const int pl = (col - off1) & 63;
        const bool wr = (col >= off1) && (col < off1 + 32);
        const int tt = col - off1;
#pragma unroll
        for (int r = 0; r < 8; ++r) {
            float hv = fmaxf(h[r], 0.f);
            float hp0 = __shfl(hv, pl, 64);   // partner = tap0 = h[t-dil]
            if (wr) {
                const int c = wv * 8 + r;
                lds[10240 + c * 32 + (tt ^ (((c >> 4) & 3) << 3))] = pkrtz(hp0, hv);
            }
        }
    }
    __syncthreads();

    // ---- phase 2: f,g (4o x 4t x 16c per thread) + tanh*relu -> s16 ----
    {
        float fa[16], ga[16];
#pragma unroll
        for (int k = 0; k < 16; ++k) { fa[k] = 0.f; ga[k] = 0.f; }
        const unsigned* fb_ = lds + q * 16 + cs * 4;
        const unsigned* gb_ = lds + 4096 + q * 16 + cs * 4;
        const unsigned* hp_ = lds + 10240 + cs * 512 + ((tg * 4) ^ (cs << 3));
#pragma unroll 2
        for (int ci = 0; ci < 16; ++ci) {
            uint4 fw4 = *(const uint4*)(fb_ + ci * 256);
            uint4 gw4 = *(const uint4*)(gb_ + ci * 256);
            uint4 hp4 = *(const uint4*)(hp_ + ci * 32);
            unsigned fwa[4] = {fw4.x, fw4.y, fw4.z, fw4.w};
            unsigned gwa[4] = {gw4.x, gw4.y, gw4.z, gw4.w};
            unsigned hpa[4] = {hp4.x, hp4.y, hp4.z, hp4.w};
#pragma unroll
            for (int oo = 0; oo < 4; ++oo)
#pragma unroll
                for (int j = 0; j < 4; ++j) {
                    fa[oo * 4 + j] = fdot2(fwa[oo], hpa[j], fa[oo * 4 + j]);
                    ga[oo * 4 + j] = fdot2(gwa[oo], hpa[j], ga[oo * 4 + j]);
                }
        }
#pragma unroll
        for (int k = 0; k < 16; ++k) {
            fa[k] += __shfl_xor(fa[k], 1, 64);
            fa[k] += __shfl_xor(fa[k], 2, 64);
            ga[k] += __shfl_xor(ga[k], 1, 64);
            ga[k] += __shfl_xor(ga[k], 2, 64);
        }
        if (cs < 2) {
            const int r0 = 4 * q + 2 * cs;
            float fb0 = filt_b[i * 64 + r0], fb1 = filt_b[i * 64 + r0 + 1];
            float gb0 = gate_b[i * 64 + r0], gb1 = gate_b[i * 64 + r0 + 1];
            uint4 sv4;
            float s0, s1;
            s0 = fast_tanh(fa[(2 * cs) * 4 + 0] + fb0) * fmaxf(ga[(2 * cs) * 4 + 0] + gb0, 0.f);
            s1 = fast_tanh(fa[(2 * cs + 1) * 4 + 0] + fb1) * fmaxf(ga[(2 * cs + 1) * 4 + 0] + gb1, 0.f);
            sv4.x = pkrtz(s0, s1);
            s0 = fast_tanh(fa[(2 * cs) * 4 + 1] + fb0) * fmaxf(ga[(2 * cs) * 4 + 1] + gb0, 0.f);
            s1 = fast_tanh(fa[(2 * cs + 1) * 4 + 1] + fb1) * fmaxf(ga[(2 * cs + 1) * 4 + 1] + gb1, 0.f);
            sv4.y = pkrtz(s0, s1);
            s0 = fast_tanh(fa[(2 * cs) * 4 + 2] + fb0) * fmaxf(ga[(2 * cs) * 4 + 2] + gb0, 0.f);
            s1 = fast_tanh(fa[(2 * cs + 1) * 4 + 2] + fb1) * fmaxf(ga[(2 * cs + 1) * 4 + 2] + gb1, 0.f);
            sv4.z = pkrtz(s0, s1);
            s0 = fast_tanh(fa[(2 * cs) * 4 + 3] + fb0) * fmaxf(ga[(2 * cs) * 4 + 3] + gb0, 0.f);
            s1 = fast_tanh(fa[(2 * cs + 1) * 4 + 3] + fb1) * fmaxf(ga[(2 * cs + 1) * 4 + 3] + gb1, 0.f);
            sv4.w = pkrtz(s0, s1);
            const int row = 2 * q + cs;
            const int k = ((row >> 3) ^ row) & 3;
            *(uint4*)(lds + 12288 + row * 32 + ((tg * 4) ^ (k << 3))) = sv4;
        }
    }
    __syncthreads();

    // ---- phase 3: post conv -> packed f16 skip partial to ws ----
    {
        float pa[16];
#pragma unroll
        for (int k = 0; k < 16; ++k) pa[k] = 0.f;
        const unsigned* pb_ = lds + 8192 + q * 16 + cs * 4;
#pragma unroll 2
        for (int cpi = 0; cpi < 8; ++cpi) {
            uint4 pw4 = *(const uint4*)(pb_ + cpi * 256);
            const int cp = cs * 8 + cpi;
            const int k = ((cp >> 3) ^ cp) & 3;
            uint4 sv4 = *(const uint4*)(lds + 12288 + cp * 32 + ((tg * 4) ^ (k << 3)));
            unsigned pwa[4] = {pw4.x, pw4.y, pw4.z, pw4.w};
            unsigned sva[4] = {sv4.x, sv4.y, sv4.z, sv4.w};
#pragma unroll
            for (int oo = 0; oo < 4; ++oo)
#pragma unroll
                for (int j = 0; j < 4; ++j)
                    pa[oo * 4 + j] = fdot2(pwa[oo], sva[j], pa[oo * 4 + j]);
        }
#pragma unroll
        for (int k = 0; k < 16; ++k) {
            pa[k] += __shfl_xor(pa[k], 1, 64);
            pa[k] += __shfl_xor(pa[k], 2, 64);
        }
        if (cs < 2) {
            const int o0 = 4 * q + 2 * cs;
            float pb0 = post_b[i * 64 + o0], pb1 = post_b[i * 64 + o0 + 1];
            uint4 o4;
            o4.x = pkrtz(fmaxf(pa[(2 * cs) * 4 + 0] + pb0, 0.f),
                         fmaxf(pa[(2 * cs + 1) * 4 + 0] + pb1, 0.f));
            o4.y = pkrtz(fmaxf(pa[(2 * cs) * 4 + 1] + pb0, 0.f),
                         fmaxf(pa[(2 * cs + 1) * 4 + 1] + pb1, 0.f));
            o4.z = pkrtz(fmaxf(pa[(2 * cs) * 4 + 2] + pb0, 0.f),
                         fmaxf(pa[(2 * cs + 1) * 4 + 2] + pb1, 0.f));
            o4.w = pkrtz(fmaxf(pa[(2 * cs) * 4 + 3] + pb0, 0.f),
                         fmaxf(pa[(2 * cs + 1) * 4 + 3] + pb1, 0.f));
            *(uint4*)(pout + (size_t)(i * 256 + bt) * 1024 + (2 * q + cs) * 32 + tg * 4) = o4;
        }
    }
}

// ---------------- head: skip-sum + dense 64 -> 128 -> 1 ----------------
__global__ __launch_bounds__(512) void wavenet_head16(
    const unsigned* __restrict__ pin,
    const float* __restrict__ d1_w, const float* __restrict__ d1_b,
    const float* __restrict__ d2_w, const float* __restrict__ d2_b,
    float* __restrict__ out)
{
    __shared__ __align__(16) float accf[64 * 33];
    __shared__ float red[512];
    const int tid = threadIdx.x;
    const int bt = blockIdx.x;          // b*8 + tile
    const int q = tid >> 5, tt = tid & 31;

    float a[4] = {0.f, 0.f, 0.f, 0.f};
#pragma unroll
    for (int l = 0; l < 8; ++l) {
        const unsigned* p = pin + (size_t)(l * 256 + bt) * 1024;
        half2_t h0 = h2(p[(2 * q) * 32 + tt]);
        half2_t h1 = h2(p[(2 * q + 1) * 32 + tt]);
        a[0] += (float)h0[0]; a[1] += (float)h0[1];
        a[2] += (float)h1[0]; a[3] += (float)h1[1];
    }
#pragma unroll
    for (int oo = 0; oo < 4; ++oo) accf[(4 * q + oo) * 33 + tt] = a[oo];
    __syncthreads();

    {
        const int pg = tid >> 5;  // 16 groups x 8 p
        float partial = 0.f;
#pragma unroll
        for (int pp = 0; pp < 8; ++pp) {
            const int p = pg * 8 + pp;
            float z = d1_b[p];
            const float4* w4 = (const float4*)(d1_w + p * 64);
#pragma unroll 4
            for (int c4 = 0; c4 < 16; ++c4) {
                float4 w = w4[c4];
                z = fmaf(w.x, accf[(c4 * 4 + 0) * 33 + tt], z);
                z = fmaf(w.y, accf[(c4 * 4 + 1) * 33 + tt], z);
                z = fmaf(w.z, accf[(c4 * 4 + 2) * 33 + tt], z);
                z = fmaf(w.w, accf[(c4 * 4 + 3) * 33 + tt], z);
            }
            partial = fmaf(d2_w[p], fmaxf(z, 0.f), partial);
        }
        red[pg * 32 + tt] = partial;
    }
    __syncthreads();
    if (tid < 32) {
        float sum = d2_b[0];
#pragma unroll
        for (int g = 0; g < 16; ++g) sum += red[g * 32 + tid];
        out[bt * 32 + tid] = fmaxf(sum, 0.f);
    }
}

// ================= fallback 1: round-3 fused f16 kernel =================
__global__ __launch_bounds__(512, 4) void wavenet_f16(
    const unsigned* __restrict__ wsu,
    const float* __restrict__ pre_b,
    const float* __restrict__ filt_b, const float* __restrict__ gate_b,
    const float* __restrict__ post_b,
    const float* __restrict__ d1_w, const float* __restrict__ d1_b,
    const float* __restrict__ d2_w, const float* __restrict__ d2_b,
    float* __restrict__ out)
{
    __shared__ __align__(16) unsigned lds[14336];
    const int tid = threadIdx.x;
    const int b = blockIdx.x >> 3;
    const int tile = blockIdx.x & 7;
    const int t0 = TFULL - DEC + tile * 32;
    const int lane = tid & 63;
    const int wv = __builtin_amdgcn_readfirstlane(tid >> 6);
    const int cs = tid & 3;
    const int tg = (tid >> 2) & 7;
    const int q = tid >> 5;
    const unsigned* xw = wsu + WTOT_U32 + b * 8192;

    float accp[16];
#pragma unroll
    for (int k = 0; k < 16; ++k) accp[k] = 0.f;

    for (int i = 0; i < 8; ++i) {
        const int dil = 1 << i;
        const int off1 = (dil < 32) ? dil : 32;
        {
            const float4* src = (const float4*)(wsu + i * WLAYER_U32);
            float4* dst = (float4*)lds;
            for (int j = tid; j < WLAYER_U32 / 4; j += 512) dst[j] = src[j];
        }
        __syncthreads();
        {
            const int col = lane;
            int ta = (dil >= 32) ? ((col < 32) ? (t0 - dil + col) : (t0 + col - 32))
                                 : (t0 - dil + col);
            const int tw = (ta - WIN0) & 511;
            const unsigned* xp = xw + tw;
            const unsigned* pw_g = wsu + i * WLAYER_U32 + wv * 128;
            float h[8];
#pragma unroll
            for (int r = 0; r < 8; ++r) h[r] = pre_b[i * 64 + wv * 8 + r];
#pragma unroll
            for (int cpb = 0; cpb < 4; ++cpb) {
                unsigned xv0 = xp[(cpb * 4 + 0) * 512];
                unsigned xv1 = xp[(cpb * 4 + 1) * 512];
                unsigned xv2 = xp[(cpb * 4 + 2) * 512];
                unsigned xv3 = xp[(cpb * 4 + 3) * 512];
#pragma unroll
                for (int r = 0; r < 8; ++r) {
                    uint4 wq = *(const uint4*)(pw_g + r * 16 + cpb * 4);
                    h[r] = fdot2(wq.x, xv0, h[r]);
                    h[r] = fdot2(wq.y, xv1, h[r]);
                    h[r] = fdot2(wq.z, xv2, h[r]);
                    h[r] = fdot2(wq.w, xv3, h[r]);
                }
            }
            const int pl = (col - off1) & 63;
            const bool wr = (col >= off1) && (col < off1 + 32);
            const int tt = col - off1;
#pragma unroll
            for (int r = 0; r < 8; ++r) {
                float hv = fmaxf(h[r], 0.f);
                float hp0 = __shfl(hv, pl, 64);
                if (wr) lds[11264 + (wv * 8 + r) * 32 + tt] = pkrtz(hp0, hv);
            }
        }
        __syncthreads();
        {
            float fa[16], ga[16];
#pragma unroll
            for (int k = 0; k < 16; ++k) { fa[k] = 0.f; ga[k] = 0.f; }
            const unsigned* fb_ = lds + 1024 + q * 16 + cs * 4;
            const unsigned* gb_ = lds + 5120 + q * 16 + cs * 4;
            const unsigned* hp_ = lds + 11264 + cs * 512 + tg * 4;
#pragma unroll 2
            for (int ci = 0; ci < 16; ++ci) {
                uint4 fw4 = *(const uint4*)(fb_ + ci * 256);
                uint4 gw4 = *(const uint4*)(gb_ + ci * 256);
                uint4 hp4 = *(const uint4*)(hp_ + ci * 32);
                unsigned fwa[4] = {fw4.x, fw4.y, fw4.z, fw4.w};
                unsigned gwa[4] = {gw4.x, gw4.y, gw4.z, gw4.w};
                unsigned hpa[4] = {hp4.x, hp4.y, hp4.z, hp4.w};
#pragma unroll
                for (int oo = 0; oo < 4; ++oo)
#pragma unroll
                    for (int j = 0; j < 4; ++j) {
                        fa[oo * 4 + j] = fdot2(fwa[oo], hpa[j], fa[oo * 4 + j]);
                        ga[oo * 4 + j] = fdot2(gwa[oo], hpa[j], ga[oo * 4 + j]);
                    }
            }
#pragma unroll
            for (int k = 0; k < 16; ++k) {
                fa[k] += __shfl_xor(fa[k], 1, 64);
                fa[k] += __shfl_xor(fa[k], 2, 64);
                ga[k] += __shfl_xor(ga[k], 1, 64);
                ga[k] += __shfl_xor(ga[k], 2, 64);
            }
            if (cs < 2) {
                const int r0 = 4 * q + 2 * cs;
                float fb0 = filt_b[i * 64 + r0], fb1 = filt_b[i * 64 + r0 + 1];
                float gb0 = gate_b[i * 64 + r0], gb1 = gate_b[i * 64 + r0 + 1];
                uint4 sv4;
                float s0, s1;
                s0 = fast_tanh(fa[0 + 2 * cs * 4] + fb0) * fmaxf(ga[0 + 2 * cs * 4] + gb0, 0.f);
                s1 = fast_tanh(fa[(2 * cs + 1) * 4 + 0] + fb1) * fmaxf(ga[(2 * cs + 1) * 4 + 0] + gb1, 0.f);
                sv4.x = pkrtz(s0, s1);
                s0 = fast_tanh(fa[2 * cs * 4 + 1] + fb0) * fmaxf(ga[2 * cs * 4 + 1] + gb0, 0.f);
                s1 = fast_tanh(fa[(2 * cs + 1) * 4 + 1] + fb1) * fmaxf(ga[(2 * cs + 1) * 4 + 1] + gb1, 0.f);
                sv4.y = pkrtz(s0, s1);
                s0 = fast_tanh(fa[2 * cs * 4 + 2] + fb0) * fmaxf(ga[2 * cs * 4 + 2] + gb0, 0.f);
                s1 = fast_tanh(fa[(2 * cs + 1) * 4 + 2] + fb1) * fmaxf(ga[(2 * cs + 1) * 4 + 2] + gb1, 0.f);
                sv4.z = pkrtz(s0, s1);
                s0 = fast_tanh(fa[2 * cs * 4 + 3] + fb0) * fmaxf(ga[2 * cs * 4 + 3] + gb0, 0.f);
                s1 = fast_tanh(fa[(2 * cs + 1) * 4 + 3] + fb1) * fmaxf(ga[(2 * cs + 1) * 4 + 3] + gb1, 0.f);
                sv4.w = pkrtz(s0, s1);
                *(uint4*)(lds + 13312 + (2 * q + cs) * 32 + tg * 4) = sv4;
            }
        }
        __syncthreads();
        {
            float pa[16];
#pragma unroll
            for (int k = 0; k < 16; ++k) pa[k] = 0.f;
            const unsigned* pb_ = lds + 9216 + q * 16 + cs * 4;
            const unsigned* sp_ = lds + 13312 + cs * 256 + tg * 4;
#pragma unroll 2
            for (int cpi = 0; cpi < 8; ++cpi) {
                uint4 pw4 = *(const uint4*)(pb_ + cpi * 256);
                uint4 sv4 = *(const uint4*)(sp_ + cpi * 32);
                unsigned pwa[4] = {pw4.x, pw4.y, pw4.z, pw4.w};
                unsigned sva[4] = {sv4.x, sv4.y, sv4.z, sv4.w};
#pragma unroll
                for (int oo = 0; oo < 4; ++oo)
#pragma unroll
                    for (int j = 0; j < 4; ++j)
                        pa[oo * 4 + j] = fdot2(pwa[oo], sva[j], pa[oo * 4 + j]);
            }
#pragma unroll
            for (int k = 0; k < 16; ++k) {
                pa[k] += __shfl_xor(pa[k], 1, 64);
                pa[k] += __shfl_xor(pa[k], 2, 64);
            }
#pragma unroll
            for (int oo = 0; oo < 4; ++oo) {
                float pb = post_b[i * 64 + 4 * q + oo];
#pragma unroll
                for (int j = 0; j < 4; ++j)
                    accp[oo * 4 + j] += fmaxf(pa[oo * 4 + j] + pb, 0.f);
            }
        }
        __syncthreads();
    }

    float* accf = (float*)lds;
    if (cs == 0) {
#pragma unroll
        for (int oo = 0; oo < 4; ++oo)
#pragma unroll
            for (int j = 0; j < 4; ++j)
                accf[(4 * q + oo) * 33 + (4 * tg + j)] = accp[oo * 4 + j];
    }
    __syncthreads();
    {
        float* red = (float*)(lds + 11264);
        const int pg = tid >> 5, tt = tid & 31;
        float partial = 0.f;
#pragma unroll
        for (int pp = 0; pp < 8; ++pp) {
            const int p = pg * 8 + pp;
            float z = d1_b[p];
            const float4* w4 = (const float4*)(d1_w + p * 64);
#pragma unroll 4
            for (int c4 = 0; c4 < 16; ++c4) {
                float4 w = w4[c4];
                z = fmaf(w.x, accf[(c4 * 4 + 0) * 33 + tt], z);
                z = fmaf(w.y, accf[(c4 * 4 + 1) * 33 + tt], z);
                z = fmaf(w.z, accf[(c4 * 4 + 2) * 33 + tt], z);
                z = fmaf(w.w, accf[(c4 * 4 + 3) * 33 + tt], z);
            }
            partial = fmaf(d2_w[p], fmaxf(z, 0.f), partial);
        }
        red[pg * 32 + tt] = partial;
    }
    __syncthreads();
    if (tid < 32) {
        float* red = (float*)(lds + 11264);
        float sum = d2_b[0];
#pragma unroll
        for (int g = 0; g < 16; ++g) sum += red[g * 32 + tid];
        out[b * DEC + tile * 32 + tid] = fmaxf(sum, 0.f);
    }
}

// ================= fallback 2: fp32 fused (no ws) =================
#define HROW 164
#define SROW 33
__global__ __launch_bounds__(512) void wavenet_main(
    const float* __restrict__ x,
    const float* __restrict__ pre_w, const float* __restrict__ pre_b,
    const float* __restrict__ filt_w, const float* __restrict__ filt_b,
    const float* __restrict__ gate_w, const float* __restrict__ gate_b,
    const float* __restrict__ post_w, const float* __restrict__ post_b,
    const float* __restrict__ d1_w, const float* __restrict__ d1_b,
    const float* __restrict__ d2_w, const float* __restrict__ d2_b,
    float* __restrict__ out)
{
    __shared__ __align__(16) float h_s[64 * HROW];
    __shared__ __align__(16) float wbuf[20480];
    __shared__ __align__(16) float s_s[64 * SROW];
    const int tid = threadIdx.x;
    const int b = blockIdx.x >> 3;
    const int tile = blockIdx.x & 7;
    const int t0 = TFULL - DEC + tile * 32;
    const int lane = tid & 63;
    const int wv = __builtin_amdgcn_readfirstlane(tid >> 6);
    const int q = tid >> 5;
    const int tt = tid & 31;
    float accp[4] = {0.f, 0.f, 0.f, 0.f};
    for (int i = 0; i < 8; ++i) {
        const int dil = 1 << i;
        const int NC = 32 + dil;
        for (int m = tid; m < 8192; m += 512) {
            int c = m >> 7, rem = m & 127, o = rem >> 1, k = m & 1;
            wbuf[m] = filt_w[((i * 64 + o) * 64 + c) * 2 + k];
            wbuf[8192 + m] = gate_w[((i * 64 + o) * 64 + c) * 2 + k];
        }
        for (int m = tid; m < 4096; m += 512) {
            int c = m >> 6, o = m & 63;
            wbuf[16384 + m] = post_w[(i * 64 + o) * 64 + c];
        }
        __syncthreads();
        {
            const float* preb = pre_b + i * 64 + wv * 8;
            const float* prew = pre_w + (i * 64 + wv * 8) * 32;
            for (int col = lane; col < NC; col += 64) {
                int ta = t0 - dil + col;
                const float* xp = x + (size_t)b * 32 * TFULL + ta;
                float hacc[8];
#pragma unroll
                for (int r = 0; r < 8; ++r) hacc[r] = preb[r];
                for (int ci = 0; ci < 32; ++ci) {
                    float xv = xp[ci * TFULL];
#pragma unroll
                    for (int r = 0; r < 8; ++r)
                        hacc[r] = fmaf(prew[r * 32 + ci], xv, hacc[r]);
                }
#pragma unroll
                for (int r = 0; r < 8; ++r)
                    h_s[(wv * 8 + r) * HROW + col] = fmaxf(hacc[r], 0.f);
            }
        }
        __syncthreads();
        {
            float fa[4], ga[4];
#pragma unroll
            for (int oo = 0; oo < 4; ++oo) {
                fa[oo] = filt_b[i * 64 + q * 4 + oo];
                ga[oo] = gate_b[i * 64 + q * 4 + oo];
            }
            const float4* fw4 = (const float4*)wbuf;
            const float4* gw4 = (const float4*)(wbuf + 8192);
            const float* hrow0 = h_s + tt;
            const float* hrow1 = h_s + tt + dil;
#pragma unroll 4
            for (int c = 0; c < 64; ++c) {
                float4 f0 = fw4[c * 32 + q * 2];
                float4 f1 = fw4[c * 32 + q * 2 + 1];
                float4 g0 = gw4[c * 32 + q * 2];
                float4 g1 = gw4[c * 32 + q * 2 + 1];
                float h0 = hrow0[c * HROW];
                float h1 = hrow1[c * HROW];
                fa[0] = fmaf(f0.x, h0, fmaf(f0.y, h1, fa[0]));
                fa[1] = fmaf(f0.z, h0, fmaf(f0.w, h1, fa[1]));
                fa[2] = fmaf(f1.x, h0, fmaf(f1.y, h1, fa[2]));
                fa[3] = fmaf(f1.z, h0, fmaf(f1.w, h1, fa[3]));
                ga[0] = fmaf(g0.x, h0, fmaf(g0.y, h1, ga[0]));
                ga[1] = fmaf(g0.z, h0, fmaf(g0.w, h1, ga[1]));
                ga[2] = fmaf(g1.x, h0, fmaf(g1.y, h1, ga[2]));
                ga[3] = fmaf(g1.z, h0, fmaf(g1.w, h1, ga[3]));
            }
#pragma unroll
            for (int oo = 0; oo < 4; ++oo)
                s_s[(q * 4 + oo) * SROW + tt] = fast_tanh(fa[oo]) * fmaxf(ga[oo], 0.f);
        }
        __syncthreads();
        {
            float pa[4];
#pragma unroll
            for (int oo = 0; oo < 4; ++oo) pa[oo] = post_b[i * 64 + q * 4 + oo];
            const float4* pw4 = (const float4*)(wbuf + 16384);
#pragma unroll 4
            for (int c = 0; c < 64; ++c) {
                float4 pv = pw4[c * 16 + q];
                float sv = s_s[c * SROW + tt];
                pa[0] = fmaf(pv.x, sv, pa[0]);
                pa[1] = fmaf(pv.y, sv, pa[1]);
                pa[2] = fmaf(pv.z, sv, pa[2]);
                pa[3] = fmaf(pv.w, sv, pa[3]);
            }
#pragma unroll
            for (int oo = 0; oo < 4; ++oo) accp[oo] += fmaxf(pa[oo], 0.f);
        }
        __syncthreads();
    }
#pragma unroll
    for (int oo = 0; oo < 4; ++oo) s_s[(q * 4 + oo) * SROW + tt] = accp[oo];
    __syncthreads();
    {
        const int pg = tid >> 5;
        float partial = 0.f;
#pragma unroll
        for (int pp = 0; pp < 8; ++pp) {
            const int p = pg * 8 + pp;
            float z = d1_b[p];
            const float4* w4 = (const float4*)(d1_w + p * 64);
#pragma unroll 4
            for (int c4 = 0; c4 < 16; ++c4) {
                float4 w = w4[c4];
                z = fmaf(w.x, s_s[(c4 * 4 + 0) * SROW + tt], z);
                z = fmaf(w.y, s_s[(c4 * 4 + 1) * SROW + tt], z);
                z = fmaf(w.z, s_s[(c4 * 4 + 2) * SROW + tt], z);
                z = fmaf(w.w, s_s[(c4 * 4 + 3) * SROW + tt], z);
            }
            partial = fmaf(d2_w[p], fmaxf(z, 0.f), partial);
        }
        h_s[pg * 32 + tt] = partial;
    }
    __syncthreads();
    if (tid < 32) {
        float sum = d2_b[0];
#pragma unroll
        for (int g = 0; g < 16; ++g) sum += h_s[g * 32 + tid];
        out[b * DEC + tile * 32 + tid] = fmaxf(sum, 0.f);
    }
}

extern "C" void kernel_launch(void* const* d_in, const int* in_sizes, int n_in,
                              void* d_out, int out_size, void* d_ws, size_t ws_size,
                              hipStream_t stream)
{
    const float* x      = (const float*)d_in[0];
    const float* pre_w  = (const float*)d_in[1];
    const float* pre_b  = (const float*)d_in[2];
    const float* filt_w = (const float*)d_in[3];
    const float* filt_b = (const float*)d_in[4];
    const float* gate_w = (const float*)d_in[5];
    const float* gate_b = (const float*)d_in[6];
    const float* post_w = (const float*)d_in[7];
    const float* post_b = (const float*)d_in[8];
    const float* d1_w   = (const float*)d_in[9];
    const float* d1_b   = (const float*)d_in[10];
    const float* d2_w   = (const float*)d_in[11];
    const float* d2_b   = (const float*)d_in[12];
    float* out = (float*)d_out;

    if (ws_size >= WS_NEED2) {
        unsigned* ws = (unsigned*)d_ws;
        unsigned* part = ws + WTOT_U32 + X16_U32;
        wavenet_prep16<<<688, 512, 0, stream>>>(x, pre_w, filt_w, gate_w, post_w, ws);
        wavenet_layer16<<<2048, 512, 0, stream>>>(
            ws, pre_b, filt_b, gate_b, post_b, part);
        wavenet_head16<<<256, 512, 0, stream>>>(
            part, d1_w, d1_b, d2_w, d2_b, out);
    } else if (ws_size >= WS_NEED) {
        unsigned* ws = (unsigned*)d_ws;
        wavenet_prep16<<<688, 512, 0, stream>>>(x, pre_w, filt_w, gate_w, post_w, ws);
        wavenet_f16<<<256, 512, 0, stream>>>(
            ws, pre_b, filt_b, gate_b, post_b, d1_w, d1_b, d2_w, d2_b, out);
    } else {
        wavenet_main<<<256, 512, 0, stream>>>(
            x, pre_w, pre_b, filt_w, filt_b, gate_w, gate_b, post_w, post_b,
            d1_w, d1_b, d2_w, d2_b, out);
    }
}

// Round 5
// 33.923 us; speedup vs baseline: 8.5847x; 2.3953x over previous
//
#include <hip/hip_runtime.h>

typedef _Float16 half2_t __attribute__((ext_vector_type(2)));
typedef _Float16 f16x8 __attribute__((ext_vector_type(8)));
typedef float f32x4 __attribute__((ext_vector_type(4)));

#define DEC 256
#define TFULL 4096
#define WIN0 3584               // x window start (t0min-128 = 3712 >= 3584)
#define WLAYER_U32 11264        // pre16 1024 + f 4096 + g 4096 + p 2048
#define WTOT_U32 (8 * WLAYER_U32)          // 90112
#define X16_U32 (32 * 16 * 512)            // 262144
#define P_U32 (8 * 256 * 1024)             // skip partials, f16x2 packed
#define WS_NEED2 ((size_t)(WTOT_U32 + X16_U32 + P_U32) * 4)

__device__ __forceinline__ float fast_tanh(float x) {
    float xa = fminf(fmaxf(x, -10.f), 10.f);
    float e = __expf(2.f * xa);
    return (e - 1.f) * __builtin_amdgcn_rcpf(e + 1.f);
}
__device__ __forceinline__ unsigned pk_rte(float a, float b) {
    union { _Float16 h[2]; unsigned u; } v;
    v.h[0] = (_Float16)a; v.h[1] = (_Float16)b; return v.u;
}
__device__ __forceinline__ half2_t h2(unsigned u) {
    return __builtin_bit_cast(half2_t, u);
}
__device__ __forceinline__ unsigned pkrtz(float a, float b) {
    return __builtin_bit_cast(unsigned, __builtin_amdgcn_cvt_pkrtz(a, b));
}
__device__ __forceinline__ float fdot2(unsigned w, unsigned hp, float acc) {
    return __builtin_amdgcn_fdot2(h2(w), h2(hp), acc, false);
}

// ---------------- prep: pack weights + x window to f16x2 ----------------
// per-layer block (u32):
//   [0,1024)      pre16[o64][cp16]                  (u32 = cin pair)
//   [1024,5120)   f16 [kb16][o64][e4]  u32(kb,o,e) = (fw[o][c=4kb+e][0], [1])
//   [5120,9216)   g16 same layout
//   [9216,11264)  p16 [kg8][o64][e4]   u32(kg,o,e) = (pw[o][8kg+2e], [+1])
// then x16[b32][cp16][tw512] at WTOT_U32.
__global__ __launch_bounds__(512) void wavenet_prep16(
    const float* __restrict__ x,
    const float* __restrict__ pre_w,
    const float* __restrict__ fw, const float* __restrict__ gw,
    const float* __restrict__ pw, unsigned* __restrict__ ws)
{
    int idx = blockIdx.x * 512 + threadIdx.x;
    if (idx >= WTOT_U32 + X16_U32) return;
    unsigned v;
    if (idx < WTOT_U32) {
        int i = idx / WLAYER_U32;
        int r = idx - i * WLAYER_U32;
        if (r < 1024) {
            int o = r >> 4, cp = r & 15;
            const float* p = pre_w + (i * 64 + o) * 32 + 2 * cp;
            v = pk_rte(p[0], p[1]);
        } else if (r < 5120) {
            int e2 = r - 1024;
            int kb = e2 >> 8, o = (e2 >> 2) & 63, e = e2 & 3;
            int c = 4 * kb + e;
            const float* p = fw + ((i * 64 + o) * 64 + c) * 2;
            v = pk_rte(p[0], p[1]);
        } else if (r < 9216) {
            int e2 = r - 5120;
            int kb = e2 >> 8, o = (e2 >> 2) & 63, e = e2 & 3;
            int c = 4 * kb + e;
            const float* p = gw + ((i * 64 + o) * 64 + c) * 2;
            v = pk_rte(p[0], p[1]);
        } else {
            int e3 = r - 9216;
            int kg = e3 >> 8, o = (e3 >> 2) & 63, e = e3 & 3;
            int c0 = 8 * kg + 2 * e;
            const float* p = pw + (i * 64 + o) * 64 + c0;
            v = pk_rte(p[0], p[1]);
        }
    } else {
        int e = idx - WTOT_U32;
        int b = e >> 13, r2 = e & 8191;
        int cp = r2 >> 9, tw = r2 & 511;
        const float* p = x + (size_t)(b * 32 + 2 * cp) * TFULL + WIN0 + tw;
        v = pk_rte(p[0], p[TFULL]);
    }
    ws[idx] = v;
}

// ---------------- layer-parallel MFMA kernel ----------------
// grid 2048 = layer(8) x bt(256); 512 threads; LDS 12 KB.
// LDS: hp u32[0,2048)  = [kb16][t32][e4]  (k=2c+tap, kb=c>>2, e=c&3),
//                        t swizzled: t ^ ((kb&3)<<2)
//      s  u32[2048,3072)= [kg8][t32][e4]  (k=c, kg=c>>3, e=(c&7)>>1)
//                        t swizzled: t ^ ((kg&3)<<2)
__global__ __launch_bounds__(512) void wavenet_mfma(
    const unsigned* __restrict__ wsu,
    const float* __restrict__ pre_b,
    const float* __restrict__ filt_b, const float* __restrict__ gate_b,
    const float* __restrict__ post_b,
    unsigned* __restrict__ pout)
{
    __shared__ __align__(16) unsigned lds[3072];

    const int tid = threadIdx.x;
    const int i = blockIdx.x >> 8;
    const int bt = blockIdx.x & 255;
    const int b = bt >> 3;
    const int tile = bt & 7;
    const int dil = 1 << i;
    const int off1 = (dil < 32) ? dil : 32;
    const int t0 = TFULL - DEC + tile * 32;

    const int lane = tid & 63;
    const int wv = __builtin_amdgcn_readfirstlane(tid >> 6); // wave id 0..7
    const int h4 = lane >> 4;       // 0..3 (MFMA lane group)
    const int ln = lane & 15;

    // ---- phase 1 (dot2): h = relu(pre16 . x16) for 64 cols, pair taps ----
    {
        const int col = lane;
        int ta = (dil >= 32) ? ((col < 32) ? (t0 - dil + col) : (t0 + col - 32))
                             : (t0 - dil + col);
        const int tw = (ta - WIN0) & 511;   // wrap OOB idle lanes in-window
        const unsigned* xp = wsu + WTOT_U32 + b * 8192 + tw;
        const unsigned* pw_g = wsu + i * WLAYER_U32 + wv * 128; // wave-uniform
        float h[8];
#pragma unroll
        for (int r = 0; r < 8; ++r) h[r] = pre_b[i * 64 + wv * 8 + r];
#pragma unroll
        for (int cpb = 0; cpb < 4; ++cpb) {
            unsigned xv0 = xp[(cpb * 4 + 0) * 512];
            unsigned xv1 = xp[(cpb * 4 + 1) * 512];
            unsigned xv2 = xp[(cpb * 4 + 2) * 512];
            unsigned xv3 = xp[(cpb * 4 + 3) * 512];
#pragma unroll
            for (int r = 0; r < 8; ++r) {
                uint4 wq = *(const uint4*)(pw_g + r * 16 + cpb * 4);
                h[r] = fdot2(wq.x, xv0, h[r]);
                h[r] = fdot2(wq.y, xv1, h[r]);
                h[r] = fdot2(wq.z, xv2, h[r]);
                h[r] = fdot2(wq.w, xv3, h[r]);
            }
        }
        const int pl = (col - off1) & 63;
        const bool wr = (col >= off1) && (col < off1 + 32);
        const int tt = col - off1;
#pragma unroll
        for (int r = 0; r < 8; ++r) {
            float hv = fmaxf(h[r], 0.f);
            float hp0 = __shfl(hv, pl, 64);   // partner = tap0 = h[t-dil]
            if (wr) {
                const int c = wv * 8 + r;
                const int kb = c >> 2;
                lds[(kb * 32 + (tt ^ ((kb & 3) << 2))) * 4 + (c & 3)] =
                    pkrtz(hp0, hv);
            }
        }
    }
    __syncthreads();

    // ---- phase 2 (MFMA): F,G tiles; wave w -> o-tile mt=w>>1, t-tile nt=w&1
    const int mt = wv >> 1, nt = wv & 1;
    const int t = nt * 16 + ln;
    {
        f32x4 cf = {0.f, 0.f, 0.f, 0.f};
        f32x4 cg = {0.f, 0.f, 0.f, 0.f};
        const f16x8* fwg = (const f16x8*)(wsu + i * WLAYER_U32 + 1024);
        const f16x8* gwg = (const f16x8*)(wsu + i * WLAYER_U32 + 5120);
#pragma unroll
        for (int ki = 0; ki < 4; ++ki) {
            const int kbg = 4 * ki + h4;
            f16x8 bfrag = *(const f16x8*)&lds[(kbg * 32 + (t ^ ((kbg & 3) << 2))) * 4];
            f16x8 af = fwg[kbg * 64 + mt * 16 + ln];
            f16x8 ag = gwg[kbg * 64 + mt * 16 + ln];
            cf = __builtin_amdgcn_mfma_f32_16x16x32_f16(af, bfrag, cf, 0, 0, 0);
            cg = __builtin_amdgcn_mfma_f32_16x16x32_f16(ag, bfrag, cg, 0, 0, 0);
        }
        // C/D map: row o = mt*16 + 4*h4 + reg, col t  [verified layout]
        float4 fb = *(const float4*)(filt_b + i * 64 + mt * 16 + 4 * h4);
        float4 gb = *(const float4*)(gate_b + i * 64 + mt * 16 + 4 * h4);
        float s0 = fast_tanh(cf[0] + fb.x) * fmaxf(cg[0] + gb.x, 0.f);
        float s1 = fast_tanh(cf[1] + fb.y) * fmaxf(cg[1] + gb.y, 0.f);
        float s2 = fast_tanh(cf[2] + fb.z) * fmaxf(cg[2] + gb.z, 0.f);
        float s3 = fast_tanh(cf[3] + fb.w) * fmaxf(cg[3] + gb.w, 0.f);
        // s rows c = mt*16 + 4*h4 + reg -> kg = c>>3, e = (h4&1)*2 + reg/2
        const int kg = mt * 2 + (h4 >> 1);
        const int e0 = (h4 & 1) * 2;
        uint2 sv;
        sv.x = pkrtz(s0, s1);
        sv.y = pkrtz(s2, s3);
        *(uint2*)&lds[2048 + (kg * 32 + (t ^ ((kg & 3) << 2))) * 4 + e0] = sv;
    }
    __syncthreads();

    // ---- phase 3 (MFMA): P tile per wave, K=64 -> 2 MFMA ----
    {
        f32x4 cp = {0.f, 0.f, 0.f, 0.f};
        const f16x8* pwg = (const f16x8*)(wsu + i * WLAYER_U32 + 9216);
#pragma unroll
        for (int ki = 0; ki < 2; ++ki) {
            const int kg = 4 * ki + h4;
            f16x8 bs = *(const f16x8*)&lds[2048 + (kg * 32 + (t ^ ((kg & 3) << 2))) * 4];
            f16x8 ap = pwg[kg * 64 + mt * 16 + ln];
            cp = __builtin_amdgcn_mfma_f32_16x16x32_f16(ap, bs, cp, 0, 0, 0);
        }
        float4 pb = *(const float4*)(post_b + i * 64 + mt * 16 + 4 * h4);
        float p0 = fmaxf(cp[0] + pb.x, 0.f);
        float p1 = fmaxf(cp[1] + pb.y, 0.f);
        float p2 = fmaxf(cp[2] + pb.z, 0.f);
        float p3 = fmaxf(cp[3] + pb.w, 0.f);
        // rows o = mt*16 + 4*h4 + reg; pack (even,odd) pairs -> op = o>>1
        const int op = mt * 8 + 2 * h4;
        unsigned* po = pout + (size_t)(i * 256 + bt) * 1024;
        po[op * 32 + t] = pkrtz(p0, p1);
        po[(op + 1) * 32 + t] = pkrtz(p2, p3);
    }
}

// ---------------- head: skip-sum + dense 64 -> 128 -> 1 ----------------
__global__ __launch_bounds__(512) void wavenet_head16(
    const unsigned* __restrict__ pin,
    const float* __restrict__ d1_w, const float* __restrict__ d1_b,
    const float* __restrict__ d2_w, const float* __restrict__ d2_b,
    float* __restrict__ out)
{
    __shared__ __align__(16) float accf[64 * 33];
    __shared__ float red[512];
    const int tid = threadIdx.x;
    const int bt = blockIdx.x;          // b*8 + tile
    const int q = tid >> 5, tt = tid & 31;

    float a[4] = {0.f, 0.f, 0.f, 0.f};
#pragma unroll
    for (int l = 0; l < 8; ++l) {
        const unsigned* p = pin + (size_t)(l * 256 + bt) * 1024;
        half2_t h0 = h2(p[(2 * q) * 32 + tt]);
        half2_t h1 = h2(p[(2 * q + 1) * 32 + tt]);
        a[0] += (float)h0[0]; a[1] += (float)h0[1];
        a[2] += (float)h1[0]; a[3] += (float)h1[1];
    }
#pragma unroll
    for (int oo = 0; oo < 4; ++oo) accf[(4 * q + oo) * 33 + tt] = a[oo];
    __syncthreads();

    {
        const int pg = tid >> 5;  // 16 groups x 8 p
        float partial = 0.f;
#pragma unroll
        for (int pp = 0; pp < 8; ++pp) {
            const int p = pg * 8 + pp;
            float z = d1_b[p];
            const float4* w4 = (const float4*)(d1_w + p * 64);
#pragma unroll 4
            for (int c4 = 0; c4 < 16; ++c4) {
                float4 w = w4[c4];
                z = fmaf(w.x, accf[(c4 * 4 + 0) * 33 + tt], z);
                z = fmaf(w.y, accf[(c4 * 4 + 1) * 33 + tt], z);
                z = fmaf(w.z, accf[(c4 * 4 + 2) * 33 + tt], z);
                z = fmaf(w.w, accf[(c4 * 4 + 3) * 33 + tt], z);
            }
            partial = fmaf(d2_w[p], fmaxf(z, 0.f), partial);
        }
        red[pg * 32 + tt] = partial;
    }
    __syncthreads();
    if (tid < 32) {
        float sum = d2_b[0];
#pragma unroll
        for (int g = 0; g < 16; ++g) sum += red[g * 32 + tid];
        out[bt * 32 + tid] = fmaxf(sum, 0.f);
    }
}

// ================= fallback: fp32 fused (no ws) =================
#define HROW 164
#define SROW 33
__global__ __launch_bounds__(512) void wavenet_main(
    const float* __restrict__ x,
    const float* __restrict__ pre_w, const float* __restrict__ pre_b,
    const float* __restrict__ filt_w, const float* __restrict__ filt_b,
    const float* __restrict__ gate_w, const float* __restrict__ gate_b,
    const float* __restrict__ post_w, const float* __restrict__ post_b,
    const float* __restrict__ d1_w, const float* __restrict__ d1_b,
    const float* __restrict__ d2_w, const float* __restrict__ d2_b,
    float* __restrict__ out)
{
    __shared__ __align__(16) float h_s[64 * HROW];
    __shared__ __align__(16) float wbuf[20480];
    __shared__ __align__(16) float s_s[64 * SROW];
    const int tid = threadIdx.x;
    const int b = blockIdx.x >> 3;
    const int tile = blockIdx.x & 7;
    const int t0 = TFULL - DEC + tile * 32;
    const int lane = tid & 63;
    const int wv = __builtin_amdgcn_readfirstlane(tid >> 6);
    const int q = tid >> 5;
    const int tt = tid & 31;
    float accp[4] = {0.f, 0.f, 0.f, 0.f};
    for (int i = 0; i < 8; ++i) {
        const int dil = 1 << i;
        const int NC = 32 + dil;
        for (int m = tid; m < 8192; m += 512) {
            int c = m >> 7, rem = m & 127, o = rem >> 1, k = m & 1;
            wbuf[m] = filt_w[((i * 64 + o) * 64 + c) * 2 + k];
            wbuf[8192 + m] = gate_w[((i * 64 + o) * 64 + c) * 2 + k];
        }
        for (int m = tid; m < 4096; m += 512) {
            int c = m >> 6, o = m & 63;
            wbuf[16384 + m] = post_w[(i * 64 + o) * 64 + c];
        }
        __syncthreads();
        {
            const float* preb = pre_b + i * 64 + wv * 8;
            const float* prew = pre_w + (i * 64 + wv * 8) * 32;
            for (int col = lane; col < NC; col += 64) {
                int ta = t0 - dil + col;
                const float* xp = x + (size_t)b * 32 * TFULL + ta;
                float hacc[8];
#pragma unroll
                for (int r = 0; r < 8; ++r) hacc[r] = preb[r];
                for (int ci = 0; ci < 32; ++ci) {
                    float xv = xp[ci * TFULL];
#pragma unroll
                    for (int r = 0; r < 8; ++r)
                        hacc[r] = fmaf(prew[r * 32 + ci], xv, hacc[r]);
                }
#pragma unroll
                for (int r = 0; r < 8; ++r)
                    h_s[(wv * 8 + r) * HROW + col] = fmaxf(hacc[r], 0.f);
            }
        }
        __syncthreads();
        {
            float fa[4], ga[4];
#pragma unroll
            for (int oo = 0; oo < 4; ++oo) {
                fa[oo] = filt_b[i * 64 + q * 4 + oo];
                ga[oo] = gate_b[i * 64 + q * 4 + oo];
            }
            const float4* fw4 = (const float4*)wbuf;
            const float4* gw4 = (const float4*)(wbuf + 8192);
            const float* hrow0 = h_s + tt;
            const float* hrow1 = h_s + tt + dil;
#pragma unroll 4
            for (int c = 0; c < 64; ++c) {
                float4 f0 = fw4[c * 32 + q * 2];
                float4 f1 = fw4[c * 32 + q * 2 + 1];
                float4 g0 = gw4[c * 32 + q * 2];
                float4 g1 = gw4[c * 32 + q * 2 + 1];
                float h0 = hrow0[c * HROW];
                float h1 = hrow1[c * HROW];
                fa[0] = fmaf(f0.x, h0, fmaf(f0.y, h1, fa[0]));
                fa[1] = fmaf(f0.z, h0, fmaf(f0.w, h1, fa[1]));
                fa[2] = fmaf(f1.x, h0, fmaf(f1.y, h1, fa[2]));
                fa[3] = fmaf(f1.z, h0, fmaf(f1.w, h1, fa[3]));
                ga[0] = fmaf(g0.x, h0, fmaf(g0.y, h1, ga[0]));
                ga[1] = fmaf(g0.z, h0, fmaf(g0.w, h1, ga[1]));
                ga[2] = fmaf(g1.x, h0, fmaf(g1.y, h1, ga[2]));
                ga[3] = fmaf(g1.z, h0, fmaf(g1.w, h1, ga[3]));
            }
#pragma unroll
            for (int oo = 0; oo < 4; ++oo)
                s_s[(q * 4 + oo) * SROW + tt] = fast_tanh(fa[oo]) * fmaxf(ga[oo], 0.f);
        }
        __syncthreads();
        {
            float pa[4];
#pragma unroll
            for (int oo = 0; oo < 4; ++oo) pa[oo] = post_b[i * 64 + q * 4 + oo];
            const float4* pw4 = (const float4*)(wbuf + 16384);
#pragma unroll 4
            for (int c = 0; c < 64; ++c) {
                float4 pv = pw4[c * 16 + q];
                float sv = s_s[c * SROW + tt];
                pa[0] = fmaf(pv.x, sv, pa[0]);
                pa[1] = fmaf(pv.y, sv, pa[1]);
                pa[2] = fmaf(pv.z, sv, pa[2]);
                pa[3] = fmaf(pv.w, sv, pa[3]);
            }
#pragma unroll
            for (int oo = 0; oo < 4; ++oo) accp[oo] += fmaxf(pa[oo], 0.f);
        }
        __syncthreads();
    }
#pragma unroll
    for (int oo = 0; oo < 4; ++oo) s_s[(q * 4 + oo) * SROW + tt] = accp[oo];
    __syncthreads();
    {
        const int pg = tid >> 5;
        float partial = 0.f;
#pragma unroll
        for (int pp = 0; pp < 8; ++pp) {
            const int p = pg * 8 + pp;
            float z = d1_b[p];
            const float4* w4 = (const float4*)(d1_w + p * 64);
#pragma unroll 4
            for (int c4 = 0; c4 < 16; ++c4) {
                float4 w = w4[c4];
                z = fmaf(w.x, s_s[(c4 * 4 + 0) * SROW + tt], z);
                z = fmaf(w.y, s_s[(c4 * 4 + 1) * SROW + tt], z);
                z = fmaf(w.z, s_s[(c4 * 4 + 2) * SROW + tt], z);
                z = fmaf(w.w, s_s[(c4 * 4 + 3) * SROW + tt], z);
            }
            partial = fmaf(d2_w[p], fmaxf(z, 0.f), partial);
        }
        h_s[pg * 32 + tt] = partial;
    }
    __syncthreads();
    if (tid < 32) {
        float sum = d2_b[0];
#pragma unroll
        for (int g = 0; g < 16; ++g) sum += h_s[g * 32 + tid];
        out[b * DEC + tile * 32 + tid] = fmaxf(sum, 0.f);
    }
}

extern "C" void kernel_launch(void* const* d_in, const int* in_sizes, int n_in,
                              void* d_out, int out_size, void* d_ws, size_t ws_size,
                              hipStream_t stream)
{
    const float* x      = (const float*)d_in[0];
    const float* pre_w  = (const float*)d_in[1];
    const float* pre_b  = (const float*)d_in[2];
    const float* filt_w = (const float*)d_in[3];
    const float* filt_b = (const float*)d_in[4];
    const float* gate_w = (const float*)d_in[5];
    const float* gate_b = (const float*)d_in[6];
    const float* post_w = (const float*)d_in[7];
    const float* post_b = (const float*)d_in[8];
    const float* d1_w   = (const float*)d_in[9];
    const float* d1_b   = (const float*)d_in[10];
    const float* d2_w   = (const float*)d_in[11];
    const float* d2_b   = (const float*)d_in[12];
    float* out = (float*)d_out;

    if (ws_size >= WS_NEED2) {
        unsigned* ws = (unsigned*)d_ws;
        unsigned* part = ws + WTOT_U32 + X16_U32;
        wavenet_prep16<<<688, 512, 0, stream>>>(x, pre_w, filt_w, gate_w, post_w, ws);
        wavenet_mfma<<<2048, 512, 0, stream>>>(
            ws, pre_b, filt_b, gate_b, post_b, part);
        wavenet_head16<<<256, 512, 0, stream>>>(
            part, d1_w, d1_b, d2_w, d2_b, out);
    } else {
        wavenet_main<<<256, 512, 0, stream>>>(
            x, pre_w, pre_b, filt_w, filt_b, gate_w, gate_b, post_w, post_b,
            d1_w, d1_b, d2_w, d2_b, out);
    }
}

// Round 6
// 30.596 us; speedup vs baseline: 9.5182x; 1.1087x over previous
//
#include <hip/hip_runtime.h>

typedef _Float16 half2_t __attribute__((ext_vector_type(2)));
typedef _Float16 f16x8 __attribute__((ext_vector_type(8)));
typedef float f32x4 __attribute__((ext_vector_type(4)));

#define DEC 256
#define TFULL 4096
#define WIN0 3584               // x window start (t0min-128 = 3712 >= 3584)
#define WLAYER_U32 11264        // preA 1024 + f 4096 + g 4096 + p 2048
#define WTOT_U32 (8 * WLAYER_U32)          // 90112
#define X16_U32 (32 * 512 * 16)            // 262144, x16t[b][tw512][cp16]
#define P_U32 (8 * 256 * 1024)             // skip partials, f16x2 packed
#define WS_NEED2 ((size_t)(WTOT_U32 + X16_U32 + P_U32) * 4)

#define HSTR 34                 // h LDS row stride (u32), banks 2t+c/2
#define SSTR 36                 // s LDS row stride (u32), 16B-aligned rows
#define HU (64 * HSTR)          // 2176 u32
#define LDS_U32 (HU + 32 * SSTR)  // 3328 u32 = 13312 B

__device__ __forceinline__ float fast_tanh(float x) {
    float xa = fminf(fmaxf(x, -10.f), 10.f);
    float e = __expf(2.f * xa);
    return (e - 1.f) * __builtin_amdgcn_rcpf(e + 1.f);
}
__device__ __forceinline__ unsigned pk_rte(float a, float b) {
    union { _Float16 h[2]; unsigned u; } v;
    v.h[0] = (_Float16)a; v.h[1] = (_Float16)b; return v.u;
}
__device__ __forceinline__ half2_t h2(unsigned u) {
    return __builtin_bit_cast(half2_t, u);
}
__device__ __forceinline__ unsigned pkrtz(float a, float b) {
    return __builtin_bit_cast(unsigned, __builtin_amdgcn_cvt_pkrtz(a, b));
}

// ---------------- prep: pack weights + x window to f16 ----------------
// per-layer block (u32), all in the SAME MFMA A-frag convention
// (u32 e-th element of k-group kg for row o = k-pair (8kg+2e, 8kg+2e+1)):
//   [0,1024)      preA[kg4][o64][e4]   k=cin(32)
//   [1024,5120)   f16 [kb16][o64][e4]  k=2c+tap(128): u32 = (fw[o][4kb+e][0],[1])
//   [5120,9216)   g16 same
//   [9216,11264)  p16 [kg8][o64][e4]   k=c(64):  u32 = (pw[o][8kg+2e],[+1])
// then x16t[b32][tw512][cp16] at WTOT_U32 (transposed for B-frag uint4 loads).
__global__ __launch_bounds__(512) void wavenet_prep16(
    const float* __restrict__ x,
    const float* __restrict__ pre_w,
    const float* __restrict__ fw, const float* __restrict__ gw,
    const float* __restrict__ pw, unsigned* __restrict__ ws)
{
    int idx = blockIdx.x * 512 + threadIdx.x;
    if (idx >= WTOT_U32 + X16_U32) return;
    unsigned v;
    if (idx < WTOT_U32) {
        int i = idx / WLAYER_U32;
        int r = idx - i * WLAYER_U32;
        if (r < 1024) {
            int kg = r >> 8, o = (r >> 2) & 63, e = r & 3;
            const float* p = pre_w + (i * 64 + o) * 32 + 8 * kg + 2 * e;
            v = pk_rte(p[0], p[1]);
        } else if (r < 5120) {
            int e2 = r - 1024;
            int kb = e2 >> 8, o = (e2 >> 2) & 63, e = e2 & 3;
            const float* p = fw + ((i * 64 + o) * 64 + 4 * kb + e) * 2;
            v = pk_rte(p[0], p[1]);
        } else if (r < 9216) {
            int e2 = r - 5120;
            int kb = e2 >> 8, o = (e2 >> 2) & 63, e = e2 & 3;
            const float* p = gw + ((i * 64 + o) * 64 + 4 * kb + e) * 2;
            v = pk_rte(p[0], p[1]);
        } else {
            int e3 = r - 9216;
            int kg = e3 >> 8, o = (e3 >> 2) & 63, e = e3 & 3;
            const float* p = pw + (i * 64 + o) * 64 + 8 * kg + 2 * e;
            v = pk_rte(p[0], p[1]);
        }
    } else {
        int e = idx - WTOT_U32;
        int b = e >> 13, r2 = e & 8191;
        int tw = r2 >> 4, cp = r2 & 15;
        const float* p = x + (size_t)(b * 32 + 2 * cp) * TFULL + WIN0 + tw;
        v = pk_rte(p[0], p[TFULL]);
    }
    ws[idx] = v;
}

// ---------------- layer-parallel all-MFMA kernel ----------------
// grid 2048 = layer(8) x bt(256); 512 threads; LDS 13312 B.
// Wave w: o-tile mt = w>>1; col-half nt = w&1.
__global__ __launch_bounds__(512) void wavenet_mfma2(
    const unsigned* __restrict__ wsu,
    const float* __restrict__ pre_b,
    const float* __restrict__ filt_b, const float* __restrict__ gate_b,
    const float* __restrict__ post_b,
    unsigned* __restrict__ pout)
{
    __shared__ __align__(16) unsigned lds[LDS_U32];

    const int tid = threadIdx.x;
    const int i = blockIdx.x >> 8;
    const int bt = blockIdx.x & 255;
    const int b = bt >> 3;
    const int tile = bt & 7;
    const int dil = 1 << i;
    const int off1 = (dil < 32) ? dil : 32;
    const int t0 = TFULL - DEC + tile * 32;

    const int lane = tid & 63;
    const int wv = __builtin_amdgcn_readfirstlane(tid >> 6); // 0..7
    const int h4 = lane >> 4;       // 0..3 (k-group)
    const int ln = lane & 15;       // row/col within tile
    const int mt = wv >> 1;         // o-tile
    const int nt = wv & 1;          // col-half for P2/P3

    const unsigned* xw = wsu + WTOT_U32 + b * 8192;
    const unsigned* wl = wsu + i * WLAYER_U32;

    // ---- phase 1 (MFMA): h[o64][cw64] = relu(pre . x); store [cw][o] f16 ----
    {
        f16x8 a = *(const f16x8*)(wl + (h4 * 64 + mt * 16 + ln) * 4);
        float4 pb4 = *(const float4*)(pre_b + i * 64 + mt * 16 + 4 * h4);
#pragma unroll
        for (int ct2 = 0; ct2 < 2; ++ct2) {
            const int cw = (2 * (wv & 1) + ct2) * 16 + ln;  // window col
            int ta = (dil >= 32) ? ((cw < 32) ? (t0 - dil + cw) : (t0 + cw - 32))
                                 : (t0 - dil + cw);
            const int tw = (ta - WIN0) & 511;   // wrap unused tail cols
            f16x8 bx = *(const f16x8*)(xw + tw * 16 + h4 * 4);
            f32x4 c = {0.f, 0.f, 0.f, 0.f};
            c = __builtin_amdgcn_mfma_f32_16x16x32_f16(a, bx, c, 0, 0, 0);
            // rows o = mt*16 + 4*h4 + reg, col cw
            uint2 hv;
            hv.x = pkrtz(fmaxf(c[0] + pb4.x, 0.f), fmaxf(c[1] + pb4.y, 0.f));
            hv.y = pkrtz(fmaxf(c[2] + pb4.z, 0.f), fmaxf(c[3] + pb4.w, 0.f));
            *(uint2*)&lds[cw * HSTR + mt * 8 + h4 * 2] = hv;
        }
    }
    __syncthreads();

    const int t = nt * 16 + ln;     // output col 0..31

    // ---- phase 2 (MFMA): F,G (K=128, k=2c+tap); s -> LDS [t][c] f16 ----
    {
        f32x4 cf = {0.f, 0.f, 0.f, 0.f};
        f32x4 cg = {0.f, 0.f, 0.f, 0.f};
        const unsigned* fA = wl + 1024;
        const unsigned* gA = wl + 5120;
#pragma unroll
        for (int ki = 0; ki < 4; ++ki) {
            const int kbg = 4 * ki + h4;     // c0 = 4*kbg
            const int c2 = 8 * ki + 2 * h4;  // c0/2
            uint2 lo = *(const uint2*)&lds[t * HSTR + c2];          // tap0
            uint2 hi = *(const uint2*)&lds[(t + off1) * HSTR + c2]; // tap1
            uint4 bf;
            bf.x = (lo.x & 0xffffu) | (hi.x << 16);
            bf.y = (lo.x >> 16) | (hi.x & 0xffff0000u);
            bf.z = (lo.y & 0xffffu) | (hi.y << 16);
            bf.w = (lo.y >> 16) | (hi.y & 0xffff0000u);
            f16x8 bfrag = __builtin_bit_cast(f16x8, bf);
            f16x8 af = *(const f16x8*)(fA + (kbg * 64 + mt * 16 + ln) * 4);
            f16x8 ag = *(const f16x8*)(gA + (kbg * 64 + mt * 16 + ln) * 4);
            cf = __builtin_amdgcn_mfma_f32_16x16x32_f16(af, bfrag, cf, 0, 0, 0);
            cg = __builtin_amdgcn_mfma_f32_16x16x32_f16(ag, bfrag, cg, 0, 0, 0);
        }
        float4 fb = *(const float4*)(filt_b + i * 64 + mt * 16 + 4 * h4);
        float4 gb = *(const float4*)(gate_b + i * 64 + mt * 16 + 4 * h4);
        float s0 = fast_tanh(cf[0] + fb.x) * fmaxf(cg[0] + gb.x, 0.f);
        float s1 = fast_tanh(cf[1] + fb.y) * fmaxf(cg[1] + gb.y, 0.f);
        float s2 = fast_tanh(cf[2] + fb.z) * fmaxf(cg[2] + gb.z, 0.f);
        float s3 = fast_tanh(cf[3] + fb.w) * fmaxf(cg[3] + gb.w, 0.f);
        uint2 sv;
        sv.x = pkrtz(s0, s1);
        sv.y = pkrtz(s2, s3);
        *(uint2*)&lds[HU + t * SSTR + mt * 8 + h4 * 2] = sv;
    }
    __syncthreads();

    // ---- phase 3 (MFMA): P (K=64, k=c); write packed skip partial ----
    {
        f32x4 cp = {0.f, 0.f, 0.f, 0.f};
        const unsigned* pA = wl + 9216;
#pragma unroll
        for (int ki = 0; ki < 2; ++ki) {
            const int kg = 4 * ki + h4;      // c0 = 8*kg
            f16x8 bs = *(const f16x8*)&lds[HU + t * SSTR + 4 * kg];
            f16x8 ap = *(const f16x8*)(pA + (kg * 64 + mt * 16 + ln) * 4);
            cp = __builtin_amdgcn_mfma_f32_16x16x32_f16(ap, bs, cp, 0, 0, 0);
        }
        float4 pb = *(const float4*)(post_b + i * 64 + mt * 16 + 4 * h4);
        float p0 = fmaxf(cp[0] + pb.x, 0.f);
        float p1 = fmaxf(cp[1] + pb.y, 0.f);
        float p2 = fmaxf(cp[2] + pb.z, 0.f);
        float p3 = fmaxf(cp[3] + pb.w, 0.f);
        const int op = mt * 8 + 2 * h4;      // packed o-pair index
        unsigned* po = pout + (size_t)(i * 256 + bt) * 1024;
        po[op * 32 + t] = pkrtz(p0, p1);
        po[(op + 1) * 32 + t] = pkrtz(p2, p3);
    }
}

// ---------------- head: skip-sum + dense 64 -> 128 -> 1 ----------------
__global__ __launch_bounds__(512) void wavenet_head16(
    const unsigned* __restrict__ pin,
    const float* __restrict__ d1_w, const float* __restrict__ d1_b,
    const float* __restrict__ d2_w, const float* __restrict__ d2_b,
    float* __restrict__ out)
{
    __shared__ __align__(16) float accf[64 * 33];
    __shared__ float red[512];
    const int tid = threadIdx.x;
    const int bt = blockIdx.x;          // b*8 + tile
    const int q = tid >> 5, tt = tid & 31;

    float a[4] = {0.f, 0.f, 0.f, 0.f};
#pragma unroll
    for (int l = 0; l < 8; ++l) {
        const unsigned* p = pin + (size_t)(l * 256 + bt) * 1024;
        half2_t h0 = h2(p[(2 * q) * 32 + tt]);
        half2_t h1 = h2(p[(2 * q + 1) * 32 + tt]);
        a[0] += (float)h0[0]; a[1] += (float)h0[1];
        a[2] += (float)h1[0]; a[3] += (float)h1[1];
    }
#pragma unroll
    for (int oo = 0; oo < 4; ++oo) accf[(4 * q + oo) * 33 + tt] = a[oo];
    __syncthreads();

    {
        const int pg = tid >> 5;  // 16 groups x 8 p
        float partial = 0.f;
#pragma unroll
        for (int pp = 0; pp < 8; ++pp) {
            const int p = pg * 8 + pp;
            float z = d1_b[p];
            const float4* w4 = (const float4*)(d1_w + p * 64);
#pragma unroll 4
            for (int c4 = 0; c4 < 16; ++c4) {
                float4 w = w4[c4];
                z = fmaf(w.x, accf[(c4 * 4 + 0) * 33 + tt], z);
                z = fmaf(w.y, accf[(c4 * 4 + 1) * 33 + tt], z);
                z = fmaf(w.z, accf[(c4 * 4 + 2) * 33 + tt], z);
                z = fmaf(w.w, accf[(c4 * 4 + 3) * 33 + tt], z);
            }
            partial = fmaf(d2_w[p], fmaxf(z, 0.f), partial);
        }
        red[pg * 32 + tt] = partial;
    }
    __syncthreads();
    if (tid < 32) {
        float sum = d2_b[0];
#pragma unroll
        for (int g = 0; g < 16; ++g) sum += red[g * 32 + tid];
        out[bt * 32 + tid] = fmaxf(sum, 0.f);
    }
}

// ================= fallback: fp32 fused (no ws) =================
#define HROW 164
#define SROW 33
__global__ __launch_bounds__(512) void wavenet_main(
    const float* __restrict__ x,
    const float* __restrict__ pre_w, const float* __restrict__ pre_b,
    const float* __restrict__ filt_w, const float* __restrict__ filt_b,
    const float* __restrict__ gate_w, const float* __restrict__ gate_b,
    const float* __restrict__ post_w, const float* __restrict__ post_b,
    const float* __restrict__ d1_w, const float* __restrict__ d1_b,
    const float* __restrict__ d2_w, const float* __restrict__ d2_b,
    float* __restrict__ out)
{
    __shared__ __align__(16) float h_s[64 * HROW];
    __shared__ __align__(16) float wbuf[20480];
    __shared__ __align__(16) float s_s[64 * SROW];
    const int tid = threadIdx.x;
    const int b = blockIdx.x >> 3;
    const int tile = blockIdx.x & 7;
    const int t0 = TFULL - DEC + tile * 32;
    const int lane = tid & 63;
    const int wv = __builtin_amdgcn_readfirstlane(tid >> 6);
    const int q = tid >> 5;
    const int tt = tid & 31;
    float accp[4] = {0.f, 0.f, 0.f, 0.f};
    for (int i = 0; i < 8; ++i) {
        const int dil = 1 << i;
        const int NC = 32 + dil;
        for (int m = tid; m < 8192; m += 512) {
            int c = m >> 7, rem = m & 127, o = rem >> 1, k = m & 1;
            wbuf[m] = filt_w[((i * 64 + o) * 64 + c) * 2 + k];
            wbuf[8192 + m] = gate_w[((i * 64 + o) * 64 + c) * 2 + k];
        }
        for (int m = tid; m < 4096; m += 512) {
            int c = m >> 6, o = m & 63;
            wbuf[16384 + m] = post_w[(i * 64 + o) * 64 + c];
        }
        __syncthreads();
        {
            const float* preb = pre_b + i * 64 + wv * 8;
            const float* prew = pre_w + (i * 64 + wv * 8) * 32;
            for (int col = lane; col < NC; col += 64) {
                int ta = t0 - dil + col;
                const float* xp = x + (size_t)b * 32 * TFULL + ta;
                float hacc[8];
#pragma unroll
                for (int r = 0; r < 8; ++r) hacc[r] = preb[r];
                for (int ci = 0; ci < 32; ++ci) {
                    float xv = xp[ci * TFULL];
#pragma unroll
                    for (int r = 0; r < 8; ++r)
                        hacc[r] = fmaf(prew[r * 32 + ci], xv, hacc[r]);
                }
#pragma unroll
                for (int r = 0; r < 8; ++r)
                    h_s[(wv * 8 + r) * HROW + col] = fmaxf(hacc[r], 0.f);
            }
        }
        __syncthreads();
        {
            float fa[4], ga[4];
#pragma unroll
            for (int oo = 0; oo < 4; ++oo) {
                fa[oo] = filt_b[i * 64 + q * 4 + oo];
                ga[oo] = gate_b[i * 64 + q * 4 + oo];
            }
            const float4* fw4 = (const float4*)wbuf;
            const float4* gw4 = (const float4*)(wbuf + 8192);
            const float* hrow0 = h_s + tt;
            const float* hrow1 = h_s + tt + dil;
#pragma unroll 4
            for (int c = 0; c < 64; ++c) {
                float4 f0 = fw4[c * 32 + q * 2];
                float4 f1 = fw4[c * 32 + q * 2 + 1];
                float4 g0 = gw4[c * 32 + q * 2];
                float4 g1 = gw4[c * 32 + q * 2 + 1];
                float h0 = hrow0[c * HROW];
                float h1 = hrow1[c * HROW];
                fa[0] = fmaf(f0.x, h0, fmaf(f0.y, h1, fa[0]));
                fa[1] = fmaf(f0.z, h0, fmaf(f0.w, h1, fa[1]));
                fa[2] = fmaf(f1.x, h0, fmaf(f1.y, h1, fa[2]));
                fa[3] = fmaf(f1.z, h0, fmaf(f1.w, h1, fa[3]));
                ga[0] = fmaf(g0.x, h0, fmaf(g0.y, h1, ga[0]));
                ga[1] = fmaf(g0.z, h0, fmaf(g0.w, h1, ga[1]));
                ga[2] = fmaf(g1.x, h0, fmaf(g1.y, h1, ga[2]));
                ga[3] = fmaf(g1.z, h0, fmaf(g1.w, h1, ga[3]));
            }
#pragma unroll
            for (int oo = 0; oo < 4; ++oo)
                s_s[(q * 4 + oo) * SROW + tt] = fast_tanh(fa[oo]) * fmaxf(ga[oo], 0.f);
        }
        __syncthreads();
        {
            float pa[4];
#pragma unroll
            for (int oo = 0; oo < 4; ++oo) pa[oo] = post_b[i * 64 + q * 4 + oo];
            const float4* pw4 = (const float4*)(wbuf + 16384);
#pragma unroll 4
            for (int c = 0; c < 64; ++c) {
                float4 pv = pw4[c * 16 + q];
                float sv = s_s[c * SROW + tt];
                pa[0] = fmaf(pv.x, sv, pa[0]);
                pa[1] = fmaf(pv.y, sv, pa[1]);
                pa[2] = fmaf(pv.z, sv, pa[2]);
                pa[3] = fmaf(pv.w, sv, pa[3]);
            }
#pragma unroll
            for (int oo = 0; oo < 4; ++oo) accp[oo] += fmaxf(pa[oo], 0.f);
        }
        __syncthreads();
    }
#pragma unroll
    for (int oo = 0; oo < 4; ++oo) s_s[(q * 4 + oo) * SROW + tt] = accp[oo];
    __syncthreads();
    {
        const int pg = tid >> 5;
        float partial = 0.f;
#pragma unroll
        for (int pp = 0; pp < 8; ++pp) {
            const int p = pg * 8 + pp;
            float z = d1_b[p];
            const float4* w4 = (const float4*)(d1_w + p * 64);
#pragma unroll 4
            for (int c4 = 0; c4 < 16; ++c4) {
                float4 w = w4[c4];
                z = fmaf(w.x, s_s[(c4 * 4 + 0) * SROW + tt], z);
                z = fmaf(w.y, s_s[(c4 * 4 + 1) * SROW + tt], z);
                z = fmaf(w.z, s_s[(c4 * 4 + 2) * SROW + tt], z);
                z = fmaf(w.w, s_s[(c4 * 4 + 3) * SROW + tt], z);
            }
            partial = fmaf(d2_w[p], fmaxf(z, 0.f), partial);
        }
        h_s[pg * 32 + tt] = partial;
    }
    __syncthreads();
    if (tid < 32) {
        float sum = d2_b[0];
#pragma unroll
        for (int g = 0; g < 16; ++g) sum += h_s[g * 32 + tid];
        out[b * DEC + tile * 32 + tid] = fmaxf(sum, 0.f);
    }
}

extern "C" void kernel_launch(void* const* d_in, const int* in_sizes, int n_in,
                              void* d_out, int out_size, void* d_ws, size_t ws_size,
                              hipStream_t stream)
{
    const float* x      = (const float*)d_in[0];
    const float* pre_w  = (const float*)d_in[1];
    const float* pre_b  = (const float*)d_in[2];
    const float* filt_w = (const float*)d_in[3];
    const float* filt_b = (const float*)d_in[4];
    const float* gate_w = (const float*)d_in[5];
    const float* gate_b = (const float*)d_in[6];
    const float* post_w = (const float*)d_in[7];
    const float* post_b = (const float*)d_in[8];
    const float* d1_w   = (const float*)d_in[9];
    const float* d1_b   = (const float*)d_in[10];
    const float* d2_w   = (const float*)d_in[11];
    const float* d2_b   = (const float*)d_in[12];
    float* out = (float*)d_out;

    if (ws_size >= WS_NEED2) {
        unsigned* ws = (unsigned*)d_ws;
        unsigned* part = ws + WTOT_U32 + X16_U32;
        wavenet_prep16<<<688, 512, 0, stream>>>(x, pre_w, filt_w, gate_w, post_w, ws);
        wavenet_mfma2<<<2048, 512, 0, stream>>>(
            ws, pre_b, filt_b, gate_b, post_b, part);
        wavenet_head16<<<256, 512, 0, stream>>>(
            part, d1_w, d1_b, d2_w, d2_b, out);
    } else {
        wavenet_main<<<256, 512, 0, stream>>>(
            x, pre_w, pre_b, filt_w, filt_b, gate_w, gate_b, post_w, post_b,
            d1_w, d1_b, d2_w, d2_b, out);
    }
}